// Round 18
// baseline (2403.516 us; speedup 1.0000x reference)
//
#include <hip/hip_runtime.h>
#include <hip/hip_bf16.h>

typedef __hip_bfloat16 bf16;
typedef unsigned short u16;
typedef u16 u16x4 __attribute__((ext_vector_type(4)));
typedef u16 u16x8 __attribute__((ext_vector_type(8)));
typedef __bf16 bf16x8 __attribute__((ext_vector_type(8)));
typedef float f32x4 __attribute__((ext_vector_type(4)));

#define E_DIM 1024
#define DFF_DIM 4096
#define B_SZ 4
#define S_LEN 512
#define NTOK 2048

__device__ __forceinline__ u16 f2bf(float f) {
    unsigned u = __float_as_uint(f);
    return (u16)((u + 0x7FFFu + ((u >> 16) & 1u)) >> 16);
}
__device__ __forceinline__ void gload_lds16(const u16* g, u16* l) {
    __builtin_amdgcn_global_load_lds(
        (const __attribute__((address_space(1))) unsigned int*)g,
        (__attribute__((address_space(3))) unsigned int*)l, 16, 0, 0);
}

// ---------- transpose in: (S,B,E) f32 -> (B,S,E) f32 + bf16 ----------
__global__ __launch_bounds__(256) void transpose_in(const float* __restrict__ in,
                                                    float* __restrict__ out,
                                                    u16* __restrict__ outb) {
    size_t i = (size_t)blockIdx.x * 256 + threadIdx.x;
    int e = (int)(i & 1023);
    int sb = (int)(i >> 10);
    int b = sb & 3;
    int s = sb >> 2;
    float v = in[i];
    size_t o = ((size_t)((b << 9) + s) << 10) + e;
    out[o] = v;
    outb[o] = f2bf(v);
}

// ---------- writeout: (B,S,E) f32 -> (S,B,E) f32 ----------
__global__ __launch_bounds__(256) void writeout(const float* __restrict__ y,
                                                float* __restrict__ out) {
    size_t i = (size_t)blockIdx.x * 256 + threadIdx.x;
    int e = (int)(i & 1023);
    int sb = (int)(i >> 10);
    int b = sb & 3;
    int s = sb >> 2;
    out[i] = y[((size_t)((b << 9) + s) << 10) + e];
}

// ---------- weight transpose+cvt (layer-batched): W f32 -> Wt bf16 [N][K] ----------
template<bool QKV>
__global__ __launch_bounds__(256) void cvt_wt(const float* __restrict__ W,
                                              u16* __restrict__ Wt, int K, int N,
                                              size_t wls, size_t wtls) {
    const float* Wl = W + (size_t)blockIdx.z * wls;
    u16* Wtl = Wt + (size_t)blockIdx.z * wtls;
    __shared__ u16 ts[64][72];
    const int n0 = blockIdx.x * 64, k0 = blockIdx.y * 64;
    #pragma unroll
    for (int r = 0; r < 16; ++r) {
        int idx = threadIdx.x + r * 256;
        int k = idx >> 6, n = idx & 63;
        float v;
        if (QKV) v = Wl[(size_t)((n0 + n) >> 6) * ((size_t)K * 64) + (size_t)(k0 + k) * 64 + ((n0 + n) & 63)];
        else     v = Wl[(size_t)(k0 + k) * N + n0 + n];
        ts[n][k] = f2bf(v);
    }
    __syncthreads();
    #pragma unroll
    for (int r = 0; r < 2; ++r) {
        int idx = threadIdx.x + r * 256;
        int n = idx >> 3, c = idx & 7;
        u16x8 vv = *reinterpret_cast<const u16x8*>(&ts[n][c * 8]);
        *reinterpret_cast<u16x8*>(Wtl + (size_t)(n0 + n) * K + k0 + c * 8) = vv;
    }
}

// ====== bf16 GEMM v7: depth-2 + counted vmcnt + LDS swizzle + XCD chunk mode ======
// CMAJ=false: gdiv = n-tiles (row chunks resident A); CMAJ=true: gdiv = m-tiles
// (column chunks keep each XCD's B slice L2-resident — for B-heavy GEMMs).
// EPI: 0 = bf16 out (V-cols >= vcol0 transposed); 1 = bf16 bias+relu;
//      2 = f32 bias+residual. BATCH: z = layer.
template<int BM, int EPI, bool BATCH, bool CMAJ>
__global__ __launch_bounds__(256) void gemm_bt(
    const u16* __restrict__ A,
    const u16* __restrict__ Bt,
    const float* __restrict__ bias,
    const float* __restrict__ Res, int ldres,
    void* __restrict__ Cout, int ldc, int Kfull, int KS, int gdiv,
    u16* __restrict__ vtout, int vcol0,
    size_t bstr, size_t cstr, size_t vstr)
{
    constexpr int MR = BM / 32;
    constexpr int AOPS = BM / 16;
    constexpr int BOPS = 8;
    constexpr int OPW = AOPS / 4 + BOPS / 4;
    __shared__ u16 As[3][BM * 32];
    __shared__ u16 Bs[3][128 * 32];
    const int tid = threadIdx.x;
    const int l = tid & 63, w = tid >> 6;
    const int nwg = gridDim.x;
    const int lin = blockIdx.x;
    const int wg = (lin & 7) * (nwg >> 3) + (lin >> 3);   // bijective XCD swizzle
    const int m0 = (CMAJ ? (wg % gdiv) : (wg / gdiv)) * BM;
    const int n0 = (CMAJ ? (wg / gdiv) : (wg % gdiv)) * 128;
    const int z = blockIdx.z;
    const int mw = (w >> 1) * (BM / 2), nw = (w & 1) * 64;
    const int lr = l & 15, lg = l >> 4;
    const int srow = l >> 2;
    const int schunk = (((l & 3) ^ ((l >> 3) & 3))) * 8;   // swizzled global source
    const int rsw = (lr >> 1) & 3;                          // read-side chunk XOR

    const u16* bt = Bt;
    u16* vto = vtout;
    size_t coff = 0;
    int koff = z * KS;
    if constexpr (BATCH) {
        bt += (size_t)z * bstr;
        vto += (size_t)z * vstr;
        coff = (size_t)z * cstr;
        koff = 0;
    }

    f32x4 acc[MR][4];
    #pragma unroll
    for (int mi = 0; mi < MR; ++mi)
        #pragma unroll
        for (int ni = 0; ni < 4; ++ni) acc[mi][ni] = (f32x4)(0.0f);

    const u16* ap = A + (size_t)(m0 + srow) * Kfull + koff + schunk;
    const u16* bp = bt + (size_t)(n0 + srow) * Kfull + koff + schunk;
    const int nt = KS / 32;

    // prologue: stage tiles 0 and 1
    #pragma unroll
    for (int op = w; op < AOPS; op += 4) gload_lds16(ap + (size_t)op * 16 * Kfull, &As[0][op * 512]);
    #pragma unroll
    for (int op = w; op < BOPS; op += 4) gload_lds16(bp + (size_t)op * 16 * Kfull, &Bs[0][op * 512]);
    #pragma unroll
    for (int op = w; op < AOPS; op += 4) gload_lds16(ap + (size_t)op * 16 * Kfull + 32, &As[1][op * 512]);
    #pragma unroll
    for (int op = w; op < BOPS; op += 4) gload_lds16(bp + (size_t)op * 16 * Kfull + 32, &Bs[1][op * 512]);

    for (int k = 0; k < nt; ++k) {
        if (k + 2 < nt) {
            const int kk = (k + 2) * 32;
            const int buf = (k + 2) % 3;
            #pragma unroll
            for (int op = w; op < AOPS; op += 4) gload_lds16(ap + (size_t)op * 16 * Kfull + kk, &As[buf][op * 512]);
            #pragma unroll
            for (int op = w; op < BOPS; op += 4) gload_lds16(bp + (size_t)op * 16 * Kfull + kk, &Bs[buf][op * 512]);
            asm volatile("s_waitcnt vmcnt(%0)" :: "i"(2 * OPW) : "memory");
        } else if (k + 1 < nt) {
            asm volatile("s_waitcnt vmcnt(%0)" :: "i"(OPW) : "memory");
        } else {
            asm volatile("s_waitcnt vmcnt(0)" ::: "memory");
        }
        __builtin_amdgcn_s_barrier();

        const int buf = k % 3;
        u16x8 af[MR], bfr[4];
        #pragma unroll
        for (int mi = 0; mi < MR; ++mi)
            af[mi] = *reinterpret_cast<const u16x8*>(
                &As[buf][(mw + mi * 16 + lr) * 32 + ((lg ^ rsw) * 8)]);
        #pragma unroll
        for (int ni = 0; ni < 4; ++ni)
            bfr[ni] = *reinterpret_cast<const u16x8*>(
                &Bs[buf][(nw + ni * 16 + lr) * 32 + ((lg ^ rsw) * 8)]);
        #pragma unroll
        for (int mi = 0; mi < MR; ++mi)
            #pragma unroll
            for (int ni = 0; ni < 4; ++ni)
                acc[mi][ni] = __builtin_amdgcn_mfma_f32_16x16x32_bf16(
                    __builtin_bit_cast(bf16x8, af[mi]),
                    __builtin_bit_cast(bf16x8, bfr[ni]),
                    acc[mi][ni], 0, 0, 0);
        __builtin_amdgcn_s_barrier();   // write-guard
    }

    #pragma unroll
    for (int mi = 0; mi < MR; ++mi) {
        #pragma unroll
        for (int ni = 0; ni < 4; ++ni) {
            const int gc = n0 + nw + ni * 16 + lr;
            float bv = 0.0f;
            if constexpr (EPI == 1 || EPI == 2) bv = bias[gc];
            #pragma unroll
            for (int r = 0; r < 4; ++r) {
                const int gr = m0 + mw + mi * 16 + lg * 4 + r;
                float v = acc[mi][ni][r] + bv;
                if constexpr (EPI == 1) v = fmaxf(v, 0.0f);
                if constexpr (EPI == 2) {
                    ((float*)Cout)[(size_t)gr * ldc + gc] = v + Res[(size_t)gr * ldres + gc];
                } else {
                    if (gc >= vcol0) {
                        int d = gc - vcol0, hh = d >> 6, dd = d & 63;
                        int bb = gr >> 9, tt = gr & 511;
                        vto[((size_t)((bb * 16 + hh) * 64 + dd)) * 512 + tt] = f2bf(v);
                    } else {
                        ((u16*)Cout + coff)[(size_t)gr * ldc + gc] = f2bf(v);
                    }
                }
            }
        }
    }
}

// ---------- layernorm (in-place f32 + bf16 copy) ----------
__global__ __launch_bounds__(256) void ln_kernel(float* __restrict__ X,
        const float* __restrict__ g, const float* __restrict__ bta,
        u16* __restrict__ outb) {
    __shared__ float wred[4];
    __shared__ float stat;
    float* x = X + ((size_t)blockIdx.x << 10);
    const int tid = threadIdx.x;
    float4 v = reinterpret_cast<float4*>(x)[tid];
    float s = v.x + v.y + v.z + v.w;
    #pragma unroll
    for (int off = 32; off; off >>= 1) s += __shfl_down(s, off, 64);
    if ((tid & 63) == 0) wred[tid >> 6] = s;
    __syncthreads();
    if (tid == 0) stat = (wred[0] + wred[1] + wred[2] + wred[3]) * (1.0f / 1024.0f);
    __syncthreads();
    float m = stat;
    float dx = v.x - m, dy = v.y - m, dz = v.z - m, dw = v.w - m;
    float s2 = dx * dx + dy * dy + dz * dz + dw * dw;
    #pragma unroll
    for (int off = 32; off; off >>= 1) s2 += __shfl_down(s2, off, 64);
    __syncthreads();
    if ((tid & 63) == 0) wred[tid >> 6] = s2;
    __syncthreads();
    if (tid == 0) stat = rsqrtf((wred[0] + wred[1] + wred[2] + wred[3]) * (1.0f / 1024.0f) + 1e-5f);
    __syncthreads();
    float r = stat;
    const float4 gv = reinterpret_cast<const float4*>(g)[tid];
    const float4 bv = reinterpret_cast<const float4*>(bta)[tid];
    float4 o;
    o.x = dx * r * gv.x + bv.x;
    o.y = dy * r * gv.y + bv.y;
    o.z = dz * r * gv.z + bv.z;
    o.w = dw * r * gv.w + bv.w;
    reinterpret_cast<float4*>(x)[tid] = o;
    u16x4 ob;
    ob.x = f2bf(o.x); ob.y = f2bf(o.y); ob.z = f2bf(o.z); ob.w = f2bf(o.w);
    *reinterpret_cast<u16x4*>(outb + ((size_t)blockIdx.x << 10) + (tid << 2)) = ob;
}

// ======= MFMA attention v4: swapped QK^T, in-register softmax, setprio =======
template<bool CAUSAL>
__global__ __launch_bounds__(256) void attn_mfma(
    const u16* __restrict__ Qb, int ldq,
    const u16* __restrict__ Kb, int ldk,
    const u16* __restrict__ Vt, u16* __restrict__ Ob, float inv_scale)
{
    __shared__ u16 sP[16][520];     // XOR-swizzled columns
    __shared__ float sMax[4][16];
    __shared__ float sSum[4][16];
    const int qt = blockIdx.x, h = blockIdx.y, b = blockIdx.z;
    const int tid = threadIdx.x;
    const int l = tid & 63, w = tid >> 6;
    const int lr = l & 15, lg = l >> 4;
    const int q = lr;
    const int tmax = CAUSAL ? (qt + 1) * 16 : 512;
    const int KT = CAUSAL ? ((qt + 2) >> 1) : 16;
    const int KT32 = KT * 32;

    const u16* qbase = Qb + (size_t)(b * 512 + qt * 16 + lr) * ldq + h * 64 + lg * 8;
    u16x8 qf0 = *reinterpret_cast<const u16x8*>(qbase);
    u16x8 qf1 = *reinterpret_cast<const u16x8*>(qbase + 32);

    f32x4 sacc[8];
    __builtin_amdgcn_s_setprio(1);
    #pragma unroll
    for (int ni = 0; ni < 8; ++ni) {
        const int t0 = w * 128 + ni * 16;
        if (CAUSAL && t0 >= tmax) { sacc[ni] = (f32x4)(-3.0e38f); continue; }
        const u16* kbase = Kb + (size_t)(b * 512 + t0 + lr) * ldk + h * 64 + lg * 8;
        u16x8 kf0 = *reinterpret_cast<const u16x8*>(kbase);
        u16x8 kf1 = *reinterpret_cast<const u16x8*>(kbase + 32);
        f32x4 sa = (f32x4)(0.0f);
        sa = __builtin_amdgcn_mfma_f32_16x16x32_bf16(
            __builtin_bit_cast(bf16x8, kf0), __builtin_bit_cast(bf16x8, qf0), sa, 0, 0, 0);
        sa = __builtin_amdgcn_mfma_f32_16x16x32_bf16(
            __builtin_bit_cast(bf16x8, kf1), __builtin_bit_cast(bf16x8, qf1), sa, 0, 0, 0);
        sacc[ni] = sa;
    }
    __builtin_amdgcn_s_setprio(0);
    float mx = -3.0e38f;
    #pragma unroll
    for (int ni = 0; ni < 8; ++ni) {
        const int t0 = w * 128 + ni * 16;
        #pragma unroll
        for (int r = 0; r < 4; ++r) {
            const int t = t0 + lg * 4 + r;
            float v = sacc[ni][r] * inv_scale;
            if (CAUSAL && t > qt * 16 + q) v = -3.0e38f;
            sacc[ni][r] = v;
            mx = fmaxf(mx, v);
        }
    }
    mx = fmaxf(mx, __shfl_xor(mx, 16));
    mx = fmaxf(mx, __shfl_xor(mx, 32));
    if (lg == 0) sMax[w][lr] = mx;
    __syncthreads();
    mx = fmaxf(fmaxf(sMax[0][q], sMax[1][q]), fmaxf(sMax[2][q], sMax[3][q]));

    float sum = 0.0f;
    #pragma unroll
    for (int ni = 0; ni < 8; ++ni)
        #pragma unroll
        for (int r = 0; r < 4; ++r) {
            float x = sacc[ni][r] - mx;
            float p = (x < -80.0f) ? 0.0f : __expf(x);
            sacc[ni][r] = p;
            sum += p;
        }
    sum += __shfl_xor(sum, 16);
    sum += __shfl_xor(sum, 32);
    if (lg == 0) sSum[w][lr] = sum;
    __syncthreads();
    const float inv = 1.0f / (sSum[0][q] + sSum[1][q] + sSum[2][q] + sSum[3][q]);

    const int sw = (q & 7) << 3;
    #pragma unroll
    for (int ni = 0; ni < 8; ++ni) {
        const int t0 = w * 128 + ni * 16;
        if (CAUSAL && t0 >= KT32) break;
        const int tb = t0 + lg * 4;
        unsigned p01 = (unsigned)f2bf(sacc[ni][0] * inv) | ((unsigned)f2bf(sacc[ni][1] * inv) << 16);
        unsigned p23 = (unsigned)f2bf(sacc[ni][2] * inv) | ((unsigned)f2bf(sacc[ni][3] * inv) << 16);
        *reinterpret_cast<unsigned*>(&sP[q][tb ^ sw]) = p01;
        *reinterpret_cast<unsigned*>(&sP[q][(tb + 2) ^ sw]) = p23;
    }
    __syncthreads();

    const u16* vbase = Vt + ((size_t)((b * 16 + h) * 64 + w * 16 + lr)) * 512 + lg * 8;
    const int swr = (lr & 7) << 3;
    f32x4 oa = (f32x4)(0.0f);
    __builtin_amdgcn_s_setprio(1);
    #pragma unroll 4
    for (int kt = 0; kt < KT; ++kt) {
        u16x8 pf = *reinterpret_cast<const u16x8*>(&sP[lr][(kt * 32 + lg * 8) ^ swr]);
        u16x8 vf = *reinterpret_cast<const u16x8*>(vbase + kt * 32);
        oa = __builtin_amdgcn_mfma_f32_16x16x32_bf16(
            __builtin_bit_cast(bf16x8, pf), __builtin_bit_cast(bf16x8, vf), oa, 0, 0, 0);
    }
    __builtin_amdgcn_s_setprio(0);
    #pragma unroll
    for (int r = 0; r < 4; ++r)
        Ob[(size_t)(b * 512 + qt * 16 + lg * 4 + r) * 1024 + h * 64 + w * 16 + lr] = f2bf(oa[r]);
}

extern "C" void kernel_launch(void* const* d_in, const int* in_sizes, int n_in,
                              void* d_out, int out_size, void* d_ws, size_t ws_size,
                              hipStream_t stream) {
    const float* src      = (const float*)d_in[0];
    const float* tgt      = (const float*)d_in[1];
    const float* enc_wqkv = (const float*)d_in[6];
    const float* enc_wo   = (const float*)d_in[7];
    const float* enc_bo   = (const float*)d_in[8];
    const float* enc_w1   = (const float*)d_in[9];
    const float* enc_b1   = (const float*)d_in[10];
    const float* enc_w2   = (const float*)d_in[11];
    const float* enc_b2   = (const float*)d_in[12];
    const float* enc_lg   = (const float*)d_in[13];
    const float* enc_lb   = (const float*)d_in[14];
    const float* dq_s     = (const float*)d_in[15];
    const float* dwo_s    = (const float*)d_in[16];
    const float* dbo_s    = (const float*)d_in[17];
    const float* dq_c     = (const float*)d_in[18];
    const float* dwo_c    = (const float*)d_in[19];
    const float* dbo_c    = (const float*)d_in[20];
    const float* dw1      = (const float*)d_in[21];
    const float* db1      = (const float*)d_in[22];
    const float* dw2      = (const float*)d_in[23];
    const float* db2      = (const float*)d_in[24];
    const float* dlg      = (const float*)d_in[25];
    const float* dlb      = (const float*)d_in[26];

    // ---- activations (40 MB) ----
    float* xe = (float*)d_ws;
    float* y  = xe + (size_t)NTOK * E_DIM;
    u16* xeb  = (u16*)(y + (size_t)NTOK * E_DIM);
    u16* yb   = xeb  + (size_t)NTOK * E_DIM;
    u16* qkvb = yb   + (size_t)NTOK * E_DIM;
    u16* attb = qkvb + (size_t)NTOK * 3 * E_DIM;
    u16* ffhb = qkvb;                           // alias
    u16* wtbase = attb + (size_t)NTOK * E_DIM;

    const size_t SZ_QKV = (size_t)3072 * 1024;
    const size_t SZ_E   = (size_t)1024 * 1024;
    const size_t SZ_FF  = (size_t)4096 * 1024;
    const size_t o_eqkv = 0;
    const size_t o_ewo  = o_eqkv + 4 * SZ_QKV;
    const size_t o_ew1  = o_ewo  + 4 * SZ_E;
    const size_t o_ew2  = o_ew1  + 4 * SZ_FF;
    const size_t o_dqs  = o_ew2  + 4 * SZ_FF;
    const size_t o_dwos = o_dqs  + 4 * SZ_QKV;
    const size_t o_dqc  = o_dwos + 4 * SZ_E;
    const size_t o_dwoc = o_dqc  + 4 * SZ_QKV;
    const size_t o_dw1  = o_dwoc + 4 * SZ_E;
    const size_t o_dw2  = o_dw1  + 4 * SZ_FF;
    const size_t o_vt   = o_dw2  + 4 * SZ_FF;           // shared V^T (enc/self)
    const size_t o_ck   = o_vt   + 2 * SZ_E;            // cross-K x4
    const size_t o_cvt  = o_ck   + 8 * SZ_E;            // cross V^T x4
    const size_t act_bytes = (size_t)40 * 1024 * 1024;
    const size_t need_big = act_bytes + (o_cvt + 8 * SZ_E) * 2;
    const bool big = ws_size >= need_big;

    u16* vt   = big ? (wtbase + o_vt) : (wtbase + SZ_FF);
    u16* ckb  = big ? (wtbase + o_ck) : nullptr;
    u16* cvtb = big ? (wtbase + o_cvt) : nullptr;
    const int HUGE_COL = 1 << 30;

    const size_t WQKV_L = 3 * (size_t)16 * E_DIM * 64;
    const dim3 blk(256);
    const dim3 g_attn(S_LEN / 16, 16, B_SZ);

    transpose_in<<<(NTOK * E_DIM) / 256, blk, 0, stream>>>(src, xe, xeb);
    transpose_in<<<(NTOK * E_DIM) / 256, blk, 0, stream>>>(tgt, y, yb);

    if (big) {
        cvt_wt<true ><<<dim3(48, 16, 4), blk, 0, stream>>>(enc_wqkv, wtbase + o_eqkv, 1024, 3072, WQKV_L, SZ_QKV);
        cvt_wt<false><<<dim3(16, 16, 4), blk, 0, stream>>>(enc_wo,   wtbase + o_ewo,  1024, 1024, SZ_E, SZ_E);
        cvt_wt<false><<<dim3(64, 16, 4), blk, 0, stream>>>(enc_w1,   wtbase + o_ew1,  1024, 4096, SZ_FF, SZ_FF);
        cvt_wt<false><<<dim3(16, 64, 4), blk, 0, stream>>>(enc_w2,   wtbase + o_ew2,  4096, 1024, SZ_FF, SZ_FF);
        cvt_wt<true ><<<dim3(48, 16, 4), blk, 0, stream>>>(dq_s,     wtbase + o_dqs,  1024, 3072, WQKV_L, SZ_QKV);
        cvt_wt<false><<<dim3(16, 16, 4), blk, 0, stream>>>(dwo_s,    wtbase + o_dwos, 1024, 1024, SZ_E, SZ_E);
        cvt_wt<true ><<<dim3(48, 16, 4), blk, 0, stream>>>(dq_c,     wtbase + o_dqc,  1024, 3072, WQKV_L, SZ_QKV);
        cvt_wt<false><<<dim3(16, 16, 4), blk, 0, stream>>>(dwo_c,    wtbase + o_dwoc, 1024, 1024, SZ_E, SZ_E);
        cvt_wt<false><<<dim3(64, 16, 4), blk, 0, stream>>>(dw1,      wtbase + o_dw1,  1024, 4096, SZ_FF, SZ_FF);
        cvt_wt<false><<<dim3(16, 64, 4), blk, 0, stream>>>(dw2,      wtbase + o_dw2,  4096, 1024, SZ_FF, SZ_FF);
    }

    // -------- encoder --------
    for (int i = 0; i < 4; ++i) {
        u16* p_qkv = big ? wtbase + o_eqkv + i * SZ_QKV : wtbase;
        u16* p_wo  = big ? wtbase + o_ewo  + i * SZ_E   : wtbase;
        u16* p_w1  = big ? wtbase + o_ew1  + i * SZ_FF  : wtbase;
        u16* p_w2  = big ? wtbase + o_ew2  + i * SZ_FF  : wtbase;
        const float* lg0 = enc_lg + (size_t)(i * 2 + 0) * E_DIM;
        const float* lb0 = enc_lb + (size_t)(i * 2 + 0) * E_DIM;
        const float* lg1 = enc_lg + (size_t)(i * 2 + 1) * E_DIM;
        const float* lb1 = enc_lb + (size_t)(i * 2 + 1) * E_DIM;

        if (!big) cvt_wt<true><<<dim3(48, 16, 1), blk, 0, stream>>>(enc_wqkv + i * WQKV_L, p_qkv, 1024, 3072, 0, 0);
        gemm_bt<128, 0, false, true><<<dim3(384, 1, 1), blk, 0, stream>>>(xeb, p_qkv, nullptr, nullptr, 0, qkvb, 3072, 1024, 1024, 16, vt, 2048, 0, 0, 0);
        attn_mfma<false><<<g_attn, blk, 0, stream>>>(qkvb, 3072, qkvb + 1024, 3072, vt, attb, 0.125f);
        if (!big) cvt_wt<false><<<dim3(16, 16, 1), blk, 0, stream>>>(enc_wo + (size_t)i * SZ_E, p_wo, 1024, 1024, 0, 0);
        gemm_bt<64, 2, false, false><<<dim3(256, 1, 1), blk, 0, stream>>>(attb, p_wo, enc_bo + i * E_DIM, xe, 1024, xe, 1024, 1024, 1024, 8, nullptr, HUGE_COL, 0, 0, 0);
        ln_kernel<<<NTOK, blk, 0, stream>>>(xe, lg0, lb0, xeb);
        if (!big) cvt_wt<false><<<dim3(64, 16, 1), blk, 0, stream>>>(enc_w1 + (size_t)i * SZ_FF, p_w1, 1024, 4096, 0, 0);
        gemm_bt<128, 1, false, true><<<dim3(512, 1, 1), blk, 0, stream>>>(xeb, p_w1, enc_b1 + i * DFF_DIM, nullptr, 0, ffhb, 4096, 1024, 1024, 16, nullptr, HUGE_COL, 0, 0, 0);
        if (!big) cvt_wt<false><<<dim3(16, 64, 1), blk, 0, stream>>>(enc_w2 + (size_t)i * SZ_FF, p_w2, 4096, 1024, 0, 0);
        gemm_bt<64, 2, false, false><<<dim3(256, 1, 1), blk, 0, stream>>>(ffhb, p_w2, enc_b2 + i * E_DIM, xe, 1024, xe, 1024, 4096, 4096, 8, nullptr, HUGE_COL, 0, 0, 0);
        ln_kernel<<<NTOK, blk, 0, stream>>>(xe, lg1, lb1, xeb);
    }

    // ---- batched cross K/V for all 4 decoder layers (big path) ----
    if (big) {
        gemm_bt<128, 0, true, true><<<dim3(256, 1, 4), blk, 0, stream>>>(
            xeb, wtbase + o_dqc + SZ_E, nullptr, nullptr, 0,
            ckb, 1024, 1024, 1024, 16, cvtb, 1024,
            SZ_QKV, 2 * SZ_E, 2 * SZ_E);
    }

    // -------- decoder --------
    for (int i = 0; i < 4; ++i) {
        u16* p_qkv = big ? wtbase + o_dqs  + i * SZ_QKV : wtbase;
        u16* p_wos = big ? wtbase + o_dwos + i * SZ_E   : wtbase;
        u16* p_qc  = big ? wtbase + o_dqc  + i * SZ_QKV : wtbase;
        u16* p_woc = big ? wtbase + o_dwoc + i * SZ_E   : wtbase;
        u16* p_w1  = big ? wtbase + o_dw1  + i * SZ_FF  : wtbase;
        u16* p_w2  = big ? wtbase + o_dw2  + i * SZ_FF  : wtbase;
        const float* lg0 = dlg + (size_t)(i * 3 + 0) * E_DIM;
        const float* lb0 = dlb + (size_t)(i * 3 + 0) * E_DIM;
        const float* lg1 = dlg + (size_t)(i * 3 + 1) * E_DIM;
        const float* lb1 = dlb + (size_t)(i * 3 + 1) * E_DIM;
        const float* lg2 = dlg + (size_t)(i * 3 + 2) * E_DIM;
        const float* lb2 = dlb + (size_t)(i * 3 + 2) * E_DIM;

        if (!big) cvt_wt<true><<<dim3(48, 16, 1), blk, 0, stream>>>(dq_s + i * WQKV_L, p_qkv, 1024, 3072, 0, 0);
        gemm_bt<128, 0, false, true><<<dim3(384, 1, 1), blk, 0, stream>>>(yb, p_qkv, nullptr, nullptr, 0, qkvb, 3072, 1024, 1024, 16, vt, 2048, 0, 0, 0);
        attn_mfma<true><<<g_attn, blk, 0, stream>>>(qkvb, 3072, qkvb + 1024, 3072, vt, attb, 0.125f);
        if (!big) cvt_wt<false><<<dim3(16, 16, 1), blk, 0, stream>>>(dwo_s + (size_t)i * SZ_E, p_wos, 1024, 1024, 0, 0);
        gemm_bt<64, 2, false, false><<<dim3(256, 1, 1), blk, 0, stream>>>(attb, p_wos, dbo_s + i * E_DIM, y, 1024, y, 1024, 1024, 1024, 8, nullptr, HUGE_COL, 0, 0, 0);
        ln_kernel<<<NTOK, blk, 0, stream>>>(y, lg0, lb0, yb);
        // cross-attention
        if (!big) cvt_wt<true><<<dim3(48, 16, 1), blk, 0, stream>>>(dq_c + i * WQKV_L, p_qc, 1024, 3072, 0, 0);
        gemm_bt<64, 0, false, false><<<dim3(256, 1, 1), blk, 0, stream>>>(yb, p_qc, nullptr, nullptr, 0, qkvb, 3072, 1024, 1024, 8, nullptr, HUGE_COL, 0, 0, 0);
        if (big) {
            attn_mfma<false><<<g_attn, blk, 0, stream>>>(qkvb, 3072, ckb + (size_t)i * 2 * SZ_E, 1024,
                                                         cvtb + (size_t)i * 2 * SZ_E, attb, 0.125f);
        } else {
            gemm_bt<64, 0, false, false><<<dim3(512, 1, 1), blk, 0, stream>>>(xeb, p_qc + SZ_E, nullptr, nullptr, 0, qkvb + 1024, 3072, 1024, 1024, 16, vt, 1024, 0, 0, 0);
            attn_mfma<false><<<g_attn, blk, 0, stream>>>(qkvb, 3072, qkvb + 1024, 3072, vt, attb, 0.125f);
        }
        if (!big) cvt_wt<false><<<dim3(16, 16, 1), blk, 0, stream>>>(dwo_c + (size_t)i * SZ_E, p_woc, 1024, 1024, 0, 0);
        gemm_bt<64, 2, false, false><<<dim3(256, 1, 1), blk, 0, stream>>>(attb, p_woc, dbo_c + i * E_DIM, y, 1024, y, 1024, 1024, 1024, 8, nullptr, HUGE_COL, 0, 0, 0);
        ln_kernel<<<NTOK, blk, 0, stream>>>(y, lg1, lb1, yb);
        // FFN
        if (!big) cvt_wt<false><<<dim3(64, 16, 1), blk, 0, stream>>>(dw1 + (size_t)i * SZ_FF, p_w1, 1024, 4096, 0, 0);
        gemm_bt<128, 1, false, true><<<dim3(512, 1, 1), blk, 0, stream>>>(yb, p_w1, db1 + i * DFF_DIM, nullptr, 0, ffhb, 4096, 1024, 1024, 16, nullptr, HUGE_COL, 0, 0, 0);
        if (!big) cvt_wt<false><<<dim3(16, 64, 1), blk, 0, stream>>>(dw2 + (size_t)i * SZ_FF, p_w2, 4096, 1024, 0, 0);
        gemm_bt<64, 2, false, false><<<dim3(256, 1, 1), blk, 0, stream>>>(ffhb, p_w2, db2 + i * E_DIM, y, 1024, y, 1024, 4096, 4096, 8, nullptr, HUGE_COL, 0, 0, 0);
        ln_kernel<<<NTOK, blk, 0, stream>>>(y, lg2, lb2, yb);
    }

    writeout<<<(NTOK * E_DIM) / 256, blk, 0, stream>>>(y, (float*)d_out);
}

// Round 19
// 1594.177 us; speedup vs baseline: 1.5077x; 1.5077x over previous
//
#include <hip/hip_runtime.h>
#include <hip/hip_bf16.h>

typedef __hip_bfloat16 bf16;
typedef unsigned short u16;
typedef u16 u16x4 __attribute__((ext_vector_type(4)));
typedef u16 u16x8 __attribute__((ext_vector_type(8)));
typedef __bf16 bf16x8 __attribute__((ext_vector_type(8)));
typedef float f32x4 __attribute__((ext_vector_type(4)));

#define E_DIM 1024
#define DFF_DIM 4096
#define B_SZ 4
#define S_LEN 512
#define NTOK 2048

__device__ __forceinline__ u16 f2bf(float f) {
    unsigned u = __float_as_uint(f);
    return (u16)((u + 0x7FFFu + ((u >> 16) & 1u)) >> 16);
}
__device__ __forceinline__ void gload_lds16(const u16* g, u16* l) {
    __builtin_amdgcn_global_load_lds(
        (const __attribute__((address_space(1))) unsigned int*)g,
        (__attribute__((address_space(3))) unsigned int*)l, 16, 0, 0);
}

// ---------- transpose in: (S,B,E) f32 -> (B,S,E) f32 + bf16 ----------
__global__ __launch_bounds__(256) void transpose_in(const float* __restrict__ in,
                                                    float* __restrict__ out,
                                                    u16* __restrict__ outb) {
    size_t i = (size_t)blockIdx.x * 256 + threadIdx.x;
    int e = (int)(i & 1023);
    int sb = (int)(i >> 10);
    int b = sb & 3;
    int s = sb >> 2;
    float v = in[i];
    size_t o = ((size_t)((b << 9) + s) << 10) + e;
    out[o] = v;
    outb[o] = f2bf(v);
}

// ---------- writeout: (B,S,E) f32 -> (S,B,E) f32 ----------
__global__ __launch_bounds__(256) void writeout(const float* __restrict__ y,
                                                float* __restrict__ out) {
    size_t i = (size_t)blockIdx.x * 256 + threadIdx.x;
    int e = (int)(i & 1023);
    int sb = (int)(i >> 10);
    int b = sb & 3;
    int s = sb >> 2;
    out[i] = y[((size_t)((b << 9) + s) << 10) + e];
}

// ---------- weight transpose+cvt (layer-batched): W f32 -> Wt bf16 [N][K] ----------
template<bool QKV>
__global__ __launch_bounds__(256) void cvt_wt(const float* __restrict__ W,
                                              u16* __restrict__ Wt, int K, int N,
                                              size_t wls, size_t wtls) {
    const float* Wl = W + (size_t)blockIdx.z * wls;
    u16* Wtl = Wt + (size_t)blockIdx.z * wtls;
    __shared__ u16 ts[64][72];
    const int n0 = blockIdx.x * 64, k0 = blockIdx.y * 64;
    #pragma unroll
    for (int r = 0; r < 16; ++r) {
        int idx = threadIdx.x + r * 256;
        int k = idx >> 6, n = idx & 63;
        float v;
        if (QKV) v = Wl[(size_t)((n0 + n) >> 6) * ((size_t)K * 64) + (size_t)(k0 + k) * 64 + ((n0 + n) & 63)];
        else     v = Wl[(size_t)(k0 + k) * N + n0 + n];
        ts[n][k] = f2bf(v);
    }
    __syncthreads();
    #pragma unroll
    for (int r = 0; r < 2; ++r) {
        int idx = threadIdx.x + r * 256;
        int n = idx >> 3, c = idx & 7;
        u16x8 vv = *reinterpret_cast<const u16x8*>(&ts[n][c * 8]);
        *reinterpret_cast<u16x8*>(Wtl + (size_t)(n0 + n) * K + k0 + c * 8) = vv;
    }
}

// == bf16 GEMM v8: depth-2 + counted vmcnt + LDS swizzle + coalesced V^T epilogue ==
// EPI: 0 = bf16 out (whole 128-col V tiles at n0>=vcol0 transposed coalesced);
//      1 = bf16 bias+relu; 2 = f32 bias+residual; 3 = f32 partial (split-K).
// BATCH: blockIdx.z = layer; else z = K-slice.
template<int BM, int EPI, bool BATCH>
__global__ __launch_bounds__(256) void gemm_bt(
    const u16* __restrict__ A,
    const u16* __restrict__ Bt,
    const float* __restrict__ bias,
    const float* __restrict__ Res, int ldres,
    void* __restrict__ Cout, int ldc, int Kfull, int KS, int gx,
    u16* __restrict__ vtout, int vcol0,
    size_t bstr, size_t cstr, size_t vstr)
{
    constexpr int MR = BM / 32;
    constexpr int AOPS = BM / 16;
    constexpr int BOPS = 8;
    constexpr int OPW = AOPS / 4 + BOPS / 4;
    __shared__ u16 SH[3 * BM * 32 + 3 * 128 * 32];
    u16* As = SH;
    u16* Bs = SH + 3 * BM * 32;
    const int tid = threadIdx.x;
    const int l = tid & 63, w = tid >> 6;
    const int nwg = gridDim.x;
    const int lin = blockIdx.x;
    const int wg = (lin & 7) * (nwg >> 3) + (lin >> 3);   // bijective XCD swizzle
    const int m0 = (wg / gx) * BM, n0 = (wg % gx) * 128;
    const int z = blockIdx.z;
    const int mw = (w >> 1) * (BM / 2), nw = (w & 1) * 64;
    const int lr = l & 15, lg = l >> 4;
    const int srow = l >> 2;
    const int schunk = (((l & 3) ^ ((l >> 3) & 3))) * 8;   // swizzled global source
    const int rsw = (lr >> 1) & 3;                          // read-side chunk XOR

    const u16* bt = Bt;
    u16* vto = vtout;
    size_t coff = 0;
    int koff = z * KS;
    if constexpr (BATCH) {
        bt += (size_t)z * bstr;
        vto += (size_t)z * vstr;
        coff = (size_t)z * cstr;
        koff = 0;
    }

    f32x4 acc[MR][4];
    #pragma unroll
    for (int mi = 0; mi < MR; ++mi)
        #pragma unroll
        for (int ni = 0; ni < 4; ++ni) acc[mi][ni] = (f32x4)(0.0f);

    const u16* ap = A + (size_t)(m0 + srow) * Kfull + koff + schunk;
    const u16* bp = bt + (size_t)(n0 + srow) * Kfull + koff + schunk;
    const int nt = KS / 32;

    // prologue: stage tiles 0 and 1
    #pragma unroll
    for (int op = w; op < AOPS; op += 4) gload_lds16(ap + (size_t)op * 16 * Kfull, &As[op * 512]);
    #pragma unroll
    for (int op = w; op < BOPS; op += 4) gload_lds16(bp + (size_t)op * 16 * Kfull, &Bs[op * 512]);
    #pragma unroll
    for (int op = w; op < AOPS; op += 4) gload_lds16(ap + (size_t)op * 16 * Kfull + 32, &As[BM * 32 + op * 512]);
    #pragma unroll
    for (int op = w; op < BOPS; op += 4) gload_lds16(bp + (size_t)op * 16 * Kfull + 32, &Bs[128 * 32 + op * 512]);

    for (int k = 0; k < nt; ++k) {
        if (k + 2 < nt) {
            const int kk = (k + 2) * 32;
            const int buf = (k + 2) % 3;
            #pragma unroll
            for (int op = w; op < AOPS; op += 4) gload_lds16(ap + (size_t)op * 16 * Kfull + kk, &As[buf * BM * 32 + op * 512]);
            #pragma unroll
            for (int op = w; op < BOPS; op += 4) gload_lds16(bp + (size_t)op * 16 * Kfull + kk, &Bs[buf * 128 * 32 + op * 512]);
            asm volatile("s_waitcnt vmcnt(%0)" :: "i"(2 * OPW) : "memory");
        } else if (k + 1 < nt) {
            asm volatile("s_waitcnt vmcnt(%0)" :: "i"(OPW) : "memory");
        } else {
            asm volatile("s_waitcnt vmcnt(0)" ::: "memory");
        }
        __builtin_amdgcn_s_barrier();

        const int buf = k % 3;
        u16x8 af[MR], bfr[4];
        #pragma unroll
        for (int mi = 0; mi < MR; ++mi)
            af[mi] = *reinterpret_cast<const u16x8*>(
                &As[buf * BM * 32 + (mw + mi * 16 + lr) * 32 + ((lg ^ rsw) * 8)]);
        #pragma unroll
        for (int ni = 0; ni < 4; ++ni)
            bfr[ni] = *reinterpret_cast<const u16x8*>(
                &Bs[buf * 128 * 32 + (nw + ni * 16 + lr) * 32 + ((lg ^ rsw) * 8)]);
        #pragma unroll
        for (int mi = 0; mi < MR; ++mi)
            #pragma unroll
            for (int ni = 0; ni < 4; ++ni)
                acc[mi][ni] = __builtin_amdgcn_mfma_f32_16x16x32_bf16(
                    __builtin_bit_cast(bf16x8, af[mi]),
                    __builtin_bit_cast(bf16x8, bfr[ni]),
                    acc[mi][ni], 0, 0, 0);
        __builtin_amdgcn_s_barrier();   // write-guard
    }

    if constexpr (EPI == 0) {
        if (n0 >= vcol0) {
            // ---- V tile: LDS transpose [n_local][m_local] then coalesced write ----
            constexpr int PSTR = BM + 4;
            #pragma unroll
            for (int mi = 0; mi < MR; ++mi)
                #pragma unroll
                for (int ni = 0; ni < 4; ++ni) {
                    const int nl = nw + ni * 16 + lr;
                    #pragma unroll
                    for (int r = 0; r < 4; ++r)
                        SH[nl * PSTR + mw + mi * 16 + lg * 4 + r] = f2bf(acc[mi][ni][r]);
                }
            __syncthreads();
            constexpr int LPR = BM / 8;          // lanes per row (16B chunks)
            constexpr int RPP = 256 / LPR;       // rows per pass
            const int row = tid / LPR, j = tid % LPR;
            const int bb = m0 >> 9, tt0 = m0 & 511;
            #pragma unroll
            for (int p = 0; p < 128 / RPP; ++p) {
                const int rr = p * RPP + row;
                const int d = n0 + rr - vcol0;
                u16x8 vv = *reinterpret_cast<const u16x8*>(&SH[rr * PSTR + j * 8]);
                *reinterpret_cast<u16x8*>(
                    vto + ((size_t)((bb * 16 + (d >> 6)) * 64 + (d & 63))) * 512 + tt0 + j * 8) = vv;
            }
            return;
        }
    }

    #pragma unroll
    for (int mi = 0; mi < MR; ++mi) {
        #pragma unroll
        for (int ni = 0; ni < 4; ++ni) {
            const int gc = n0 + nw + ni * 16 + lr;
            float bv = 0.0f;
            if constexpr (EPI == 1 || EPI == 2) bv = bias[gc];
            #pragma unroll
            for (int r = 0; r < 4; ++r) {
                const int gr = m0 + mw + mi * 16 + lg * 4 + r;
                float v = acc[mi][ni][r] + bv;
                if constexpr (EPI == 1) v = fmaxf(v, 0.0f);
                if constexpr (EPI == 2) {
                    ((float*)Cout)[(size_t)gr * ldc + gc] = v + Res[(size_t)gr * ldres + gc];
                } else if constexpr (EPI == 3) {
                    ((float*)Cout)[(size_t)z * NTOK * ldc + (size_t)gr * ldc + gc] = v;
                } else {
                    ((u16*)Cout + coff)[(size_t)gr * ldc + gc] = f2bf(v);
                }
            }
        }
    }
}

// ---------- fused split-K reduce + bias + residual + LayerNorm ----------
template<int NP>
__global__ __launch_bounds__(256) void ln_red(
    const float* __restrict__ part, const float* __restrict__ bias,
    float* __restrict__ X,
    const float* __restrict__ g, const float* __restrict__ bta,
    u16* __restrict__ outb) {
    __shared__ float wred[4];
    __shared__ float stat;
    const size_t row = blockIdx.x;
    const int tid = threadIdx.x;
    float4 v = reinterpret_cast<const float4*>(X + (row << 10))[tid];
    const float4 bb = reinterpret_cast<const float4*>(bias)[tid];
    v.x += bb.x; v.y += bb.y; v.z += bb.z; v.w += bb.w;
    #pragma unroll
    for (int s = 0; s < NP; ++s) {
        const float4 p = reinterpret_cast<const float4*>(part + ((size_t)s * NTOK + row) * 1024)[tid];
        v.x += p.x; v.y += p.y; v.z += p.z; v.w += p.w;
    }
    float sm = v.x + v.y + v.z + v.w;
    #pragma unroll
    for (int off = 32; off; off >>= 1) sm += __shfl_down(sm, off, 64);
    if ((tid & 63) == 0) wred[tid >> 6] = sm;
    __syncthreads();
    if (tid == 0) stat = (wred[0] + wred[1] + wred[2] + wred[3]) * (1.0f / 1024.0f);
    __syncthreads();
    float m = stat;
    float dx = v.x - m, dy = v.y - m, dz = v.z - m, dw = v.w - m;
    float s2 = dx * dx + dy * dy + dz * dz + dw * dw;
    #pragma unroll
    for (int off = 32; off; off >>= 1) s2 += __shfl_down(s2, off, 64);
    __syncthreads();
    if ((tid & 63) == 0) wred[tid >> 6] = s2;
    __syncthreads();
    if (tid == 0) stat = rsqrtf((wred[0] + wred[1] + wred[2] + wred[3]) * (1.0f / 1024.0f) + 1e-5f);
    __syncthreads();
    float r = stat;
    const float4 gv = reinterpret_cast<const float4*>(g)[tid];
    const float4 bv = reinterpret_cast<const float4*>(bta)[tid];
    float4 o;
    o.x = dx * r * gv.x + bv.x;
    o.y = dy * r * gv.y + bv.y;
    o.z = dz * r * gv.z + bv.z;
    o.w = dw * r * gv.w + bv.w;
    reinterpret_cast<float4*>(X + (row << 10))[tid] = o;
    u16x4 ob;
    ob.x = f2bf(o.x); ob.y = f2bf(o.y); ob.z = f2bf(o.z); ob.w = f2bf(o.w);
    *reinterpret_cast<u16x4*>(outb + (row << 10) + (tid << 2)) = ob;
}

// ---------- plain layernorm (fallback path) ----------
__global__ __launch_bounds__(256) void ln_kernel(float* __restrict__ X,
        const float* __restrict__ g, const float* __restrict__ bta,
        u16* __restrict__ outb) {
    __shared__ float wred[4];
    __shared__ float stat;
    float* x = X + ((size_t)blockIdx.x << 10);
    const int tid = threadIdx.x;
    float4 v = reinterpret_cast<float4*>(x)[tid];
    float s = v.x + v.y + v.z + v.w;
    #pragma unroll
    for (int off = 32; off; off >>= 1) s += __shfl_down(s, off, 64);
    if ((tid & 63) == 0) wred[tid >> 6] = s;
    __syncthreads();
    if (tid == 0) stat = (wred[0] + wred[1] + wred[2] + wred[3]) * (1.0f / 1024.0f);
    __syncthreads();
    float m = stat;
    float dx = v.x - m, dy = v.y - m, dz = v.z - m, dw = v.w - m;
    float s2 = dx * dx + dy * dy + dz * dz + dw * dw;
    #pragma unroll
    for (int off = 32; off; off >>= 1) s2 += __shfl_down(s2, off, 64);
    __syncthreads();
    if ((tid & 63) == 0) wred[tid >> 6] = s2;
    __syncthreads();
    if (tid == 0) stat = rsqrtf((wred[0] + wred[1] + wred[2] + wred[3]) * (1.0f / 1024.0f) + 1e-5f);
    __syncthreads();
    float r = stat;
    const float4 gv = reinterpret_cast<const float4*>(g)[tid];
    const float4 bv = reinterpret_cast<const float4*>(bta)[tid];
    float4 o;
    o.x = dx * r * gv.x + bv.x;
    o.y = dy * r * gv.y + bv.y;
    o.z = dz * r * gv.z + bv.z;
    o.w = dw * r * gv.w + bv.w;
    reinterpret_cast<float4*>(x)[tid] = o;
    u16x4 ob;
    ob.x = f2bf(o.x); ob.y = f2bf(o.y); ob.z = f2bf(o.z); ob.w = f2bf(o.w);
    *reinterpret_cast<u16x4*>(outb + ((size_t)blockIdx.x << 10) + (tid << 2)) = ob;
}

// ======= MFMA attention v4: swapped QK^T, in-register softmax, setprio =======
template<bool CAUSAL>
__global__ __launch_bounds__(256) void attn_mfma(
    const u16* __restrict__ Qb, int ldq,
    const u16* __restrict__ Kb, int ldk,
    const u16* __restrict__ Vt, u16* __restrict__ Ob, float inv_scale)
{
    __shared__ u16 sP[16][520];
    __shared__ float sMax[4][16];
    __shared__ float sSum[4][16];
    const int qt = blockIdx.x, h = blockIdx.y, b = blockIdx.z;
    const int tid = threadIdx.x;
    const int l = tid & 63, w = tid >> 6;
    const int lr = l & 15, lg = l >> 4;
    const int q = lr;
    const int tmax = CAUSAL ? (qt + 1) * 16 : 512;
    const int KT = CAUSAL ? ((qt + 2) >> 1) : 16;
    const int KT32 = KT * 32;

    const u16* qbase = Qb + (size_t)(b * 512 + qt * 16 + lr) * ldq + h * 64 + lg * 8;
    u16x8 qf0 = *reinterpret_cast<const u16x8*>(qbase);
    u16x8 qf1 = *reinterpret_cast<const u16x8*>(qbase + 32);

    f32x4 sacc[8];
    __builtin_amdgcn_s_setprio(1);
    #pragma unroll
    for (int ni = 0; ni < 8; ++ni) {
        const int t0 = w * 128 + ni * 16;
        if (CAUSAL && t0 >= tmax) { sacc[ni] = (f32x4)(-3.0e38f); continue; }
        const u16* kbase = Kb + (size_t)(b * 512 + t0 + lr) * ldk + h * 64 + lg * 8;
        u16x8 kf0 = *reinterpret_cast<const u16x8*>(kbase);
        u16x8 kf1 = *reinterpret_cast<const u16x8*>(kbase + 32);
        f32x4 sa = (f32x4)(0.0f);
        sa = __builtin_amdgcn_mfma_f32_16x16x32_bf16(
            __builtin_bit_cast(bf16x8, kf0), __builtin_bit_cast(bf16x8, qf0), sa, 0, 0, 0);
        sa = __builtin_amdgcn_mfma_f32_16x16x32_bf16(
            __builtin_bit_cast(bf16x8, kf1), __builtin_bit_cast(bf16x8, qf1), sa, 0, 0, 0);
        sacc[ni] = sa;
    }
    __builtin_amdgcn_s_setprio(0);
    float mx = -3.0e38f;
    #pragma unroll
    for (int ni = 0; ni < 8; ++ni) {
        const int t0 = w * 128 + ni * 16;
        #pragma unroll
        for (int r = 0; r < 4; ++r) {
            const int t = t0 + lg * 4 + r;
            float v = sacc[ni][r] * inv_scale;
            if (CAUSAL && t > qt * 16 + q) v = -3.0e38f;
            sacc[ni][r] = v;
            mx = fmaxf(mx, v);
        }
    }
    mx = fmaxf(mx, __shfl_xor(mx, 16));
    mx = fmaxf(mx, __shfl_xor(mx, 32));
    if (lg == 0) sMax[w][lr] = mx;
    __syncthreads();
    mx = fmaxf(fmaxf(sMax[0][q], sMax[1][q]), fmaxf(sMax[2][q], sMax[3][q]));

    float sum = 0.0f;
    #pragma unroll
    for (int ni = 0; ni < 8; ++ni)
        #pragma unroll
        for (int r = 0; r < 4; ++r) {
            float x = sacc[ni][r] - mx;
            float p = (x < -80.0f) ? 0.0f : __expf(x);
            sacc[ni][r] = p;
            sum += p;
        }
    sum += __shfl_xor(sum, 16);
    sum += __shfl_xor(sum, 32);
    if (lg == 0) sSum[w][lr] = sum;
    __syncthreads();
    const float inv = 1.0f / (sSum[0][q] + sSum[1][q] + sSum[2][q] + sSum[3][q]);

    const int sw = (q & 7) << 3;
    #pragma unroll
    for (int ni = 0; ni < 8; ++ni) {
        const int t0 = w * 128 + ni * 16;
        if (CAUSAL && t0 >= KT32) break;
        const int tb = t0 + lg * 4;
        unsigned p01 = (unsigned)f2bf(sacc[ni][0] * inv) | ((unsigned)f2bf(sacc[ni][1] * inv) << 16);
        unsigned p23 = (unsigned)f2bf(sacc[ni][2] * inv) | ((unsigned)f2bf(sacc[ni][3] * inv) << 16);
        *reinterpret_cast<unsigned*>(&sP[q][tb ^ sw]) = p01;
        *reinterpret_cast<unsigned*>(&sP[q][(tb + 2) ^ sw]) = p23;
    }
    __syncthreads();

    const u16* vbase = Vt + ((size_t)((b * 16 + h) * 64 + w * 16 + lr)) * 512 + lg * 8;
    const int swr = (lr & 7) << 3;
    f32x4 oa = (f32x4)(0.0f);
    __builtin_amdgcn_s_setprio(1);
    #pragma unroll 4
    for (int kt = 0; kt < KT; ++kt) {
        u16x8 pf = *reinterpret_cast<const u16x8*>(&sP[lr][(kt * 32 + lg * 8) ^ swr]);
        u16x8 vf = *reinterpret_cast<const u16x8*>(vbase + kt * 32);
        oa = __builtin_amdgcn_mfma_f32_16x16x32_bf16(
            __builtin_bit_cast(bf16x8, pf), __builtin_bit_cast(bf16x8, vf), oa, 0, 0, 0);
    }
    __builtin_amdgcn_s_setprio(0);
    #pragma unroll
    for (int r = 0; r < 4; ++r)
        Ob[(size_t)(b * 512 + qt * 16 + lg * 4 + r) * 1024 + h * 64 + w * 16 + lr] = f2bf(oa[r]);
}

extern "C" void kernel_launch(void* const* d_in, const int* in_sizes, int n_in,
                              void* d_out, int out_size, void* d_ws, size_t ws_size,
                              hipStream_t stream) {
    const float* src      = (const float*)d_in[0];
    const float* tgt      = (const float*)d_in[1];
    const float* enc_wqkv = (const float*)d_in[6];
    const float* enc_wo   = (const float*)d_in[7];
    const float* enc_bo   = (const float*)d_in[8];
    const float* enc_w1   = (const float*)d_in[9];
    const float* enc_b1   = (const float*)d_in[10];
    const float* enc_w2   = (const float*)d_in[11];
    const float* enc_b2   = (const float*)d_in[12];
    const float* enc_lg   = (const float*)d_in[13];
    const float* enc_lb   = (const float*)d_in[14];
    const float* dq_s     = (const float*)d_in[15];
    const float* dwo_s    = (const float*)d_in[16];
    const float* dbo_s    = (const float*)d_in[17];
    const float* dq_c     = (const float*)d_in[18];
    const float* dwo_c    = (const float*)d_in[19];
    const float* dbo_c    = (const float*)d_in[20];
    const float* dw1      = (const float*)d_in[21];
    const float* db1      = (const float*)d_in[22];
    const float* dw2      = (const float*)d_in[23];
    const float* db2      = (const float*)d_in[24];
    const float* dlg      = (const float*)d_in[25];
    const float* dlb      = (const float*)d_in[26];

    // ---- activations (40 MB) ----
    float* xe = (float*)d_ws;
    float* y  = xe + (size_t)NTOK * E_DIM;
    u16* xeb  = (u16*)(y + (size_t)NTOK * E_DIM);
    u16* yb   = xeb  + (size_t)NTOK * E_DIM;
    u16* qkvb = yb   + (size_t)NTOK * E_DIM;
    u16* attb = qkvb + (size_t)NTOK * 3 * E_DIM;
    u16* ffhb = qkvb;                           // alias
    u16* wtbase = attb + (size_t)NTOK * E_DIM;

    const size_t SZ_QKV = (size_t)3072 * 1024;
    const size_t SZ_E   = (size_t)1024 * 1024;
    const size_t SZ_FF  = (size_t)4096 * 1024;
    const size_t o_eqkv = 0;
    const size_t o_ewo  = o_eqkv + 4 * SZ_QKV;
    const size_t o_ew1  = o_ewo  + 4 * SZ_E;
    const size_t o_ew2  = o_ew1  + 4 * SZ_FF;
    const size_t o_dqs  = o_ew2  + 4 * SZ_FF;
    const size_t o_dwos = o_dqs  + 4 * SZ_QKV;
    const size_t o_dqc  = o_dwos + 4 * SZ_E;
    const size_t o_dwoc = o_dqc  + 4 * SZ_QKV;
    const size_t o_dw1  = o_dwoc + 4 * SZ_E;
    const size_t o_dw2  = o_dw1  + 4 * SZ_FF;
    const size_t o_vt   = o_dw2  + 4 * SZ_FF;
    const size_t o_part = o_vt   + 2 * SZ_E;
    const size_t o_ck   = o_part + 16 * SZ_E;
    const size_t o_cvt  = o_ck   + 8 * SZ_E;
    const size_t act_bytes = (size_t)40 * 1024 * 1024;
    const size_t need_big = act_bytes + (o_cvt + 8 * SZ_E) * 2;
    const bool big = ws_size >= need_big;

    u16* vt   = big ? (wtbase + o_vt) : (wtbase + SZ_FF);
    float* part = big ? (float*)(wtbase + o_part) : nullptr;
    u16* ckb  = big ? (wtbase + o_ck) : nullptr;
    u16* cvtb = big ? (wtbase + o_cvt) : nullptr;
    const int HUGE_COL = 1 << 30;

    const size_t WQKV_L = 3 * (size_t)16 * E_DIM * 64;
    const dim3 blk(256);
    const dim3 g_attn(S_LEN / 16, 16, B_SZ);

    transpose_in<<<(NTOK * E_DIM) / 256, blk, 0, stream>>>(src, xe, xeb);
    transpose_in<<<(NTOK * E_DIM) / 256, blk, 0, stream>>>(tgt, y, yb);

    if (big) {
        cvt_wt<true ><<<dim3(48, 16, 4), blk, 0, stream>>>(enc_wqkv, wtbase + o_eqkv, 1024, 3072, WQKV_L, SZ_QKV);
        cvt_wt<false><<<dim3(16, 16, 4), blk, 0, stream>>>(enc_wo,   wtbase + o_ewo,  1024, 1024, SZ_E, SZ_E);
        cvt_wt<false><<<dim3(64, 16, 4), blk, 0, stream>>>(enc_w1,   wtbase + o_ew1,  1024, 4096, SZ_FF, SZ_FF);
        cvt_wt<false><<<dim3(16, 64, 4), blk, 0, stream>>>(enc_w2,   wtbase + o_ew2,  4096, 1024, SZ_FF, SZ_FF);
        cvt_wt<true ><<<dim3(48, 16, 4), blk, 0, stream>>>(dq_s,     wtbase + o_dqs,  1024, 3072, WQKV_L, SZ_QKV);
        cvt_wt<false><<<dim3(16, 16, 4), blk, 0, stream>>>(dwo_s,    wtbase + o_dwos, 1024, 1024, SZ_E, SZ_E);
        cvt_wt<true ><<<dim3(48, 16, 4), blk, 0, stream>>>(dq_c,     wtbase + o_dqc,  1024, 3072, WQKV_L, SZ_QKV);
        cvt_wt<false><<<dim3(16, 16, 4), blk, 0, stream>>>(dwo_c,    wtbase + o_dwoc, 1024, 1024, SZ_E, SZ_E);
        cvt_wt<false><<<dim3(64, 16, 4), blk, 0, stream>>>(dw1,      wtbase + o_dw1,  1024, 4096, SZ_FF, SZ_FF);
        cvt_wt<false><<<dim3(16, 64, 4), blk, 0, stream>>>(dw2,      wtbase + o_dw2,  4096, 1024, SZ_FF, SZ_FF);
    }

    // -------- encoder --------
    for (int i = 0; i < 4; ++i) {
        u16* p_qkv = big ? wtbase + o_eqkv + i * SZ_QKV : wtbase;
        u16* p_wo  = big ? wtbase + o_ewo  + i * SZ_E   : wtbase;
        u16* p_w1  = big ? wtbase + o_ew1  + i * SZ_FF  : wtbase;
        u16* p_w2  = big ? wtbase + o_ew2  + i * SZ_FF  : wtbase;
        const float* lg0 = enc_lg + (size_t)(i * 2 + 0) * E_DIM;
        const float* lb0 = enc_lb + (size_t)(i * 2 + 0) * E_DIM;
        const float* lg1 = enc_lg + (size_t)(i * 2 + 1) * E_DIM;
        const float* lb1 = enc_lb + (size_t)(i * 2 + 1) * E_DIM;

        if (!big) cvt_wt<true><<<dim3(48, 16, 1), blk, 0, stream>>>(enc_wqkv + i * WQKV_L, p_qkv, 1024, 3072, 0, 0);
        gemm_bt<128, 0, false><<<dim3(384, 1, 1), blk, 0, stream>>>(xeb, p_qkv, nullptr, nullptr, 0, qkvb, 3072, 1024, 1024, 24, vt, 2048, 0, 0, 0);
        attn_mfma<false><<<g_attn, blk, 0, stream>>>(qkvb, 3072, qkvb + 1024, 3072, vt, attb, 0.125f);
        if (!big) cvt_wt<false><<<dim3(16, 16, 1), blk, 0, stream>>>(enc_wo + (size_t)i * SZ_E, p_wo, 1024, 1024, 0, 0);
        if (big) {
            gemm_bt<64, 3, false><<<dim3(256, 1, 2), blk, 0, stream>>>(attb, p_wo, nullptr, nullptr, 0, part, 1024, 1024, 512, 8, nullptr, HUGE_COL, 0, 0, 0);
            ln_red<2><<<NTOK, blk, 0, stream>>>(part, enc_bo + i * E_DIM, xe, lg0, lb0, xeb);
        } else {
            gemm_bt<64, 2, false><<<dim3(256, 1, 1), blk, 0, stream>>>(attb, p_wo, enc_bo + i * E_DIM, xe, 1024, xe, 1024, 1024, 1024, 8, nullptr, HUGE_COL, 0, 0, 0);
            ln_kernel<<<NTOK, blk, 0, stream>>>(xe, lg0, lb0, xeb);
        }
        if (!big) cvt_wt<false><<<dim3(64, 16, 1), blk, 0, stream>>>(enc_w1 + (size_t)i * SZ_FF, p_w1, 1024, 4096, 0, 0);
        gemm_bt<128, 1, false><<<dim3(512, 1, 1), blk, 0, stream>>>(xeb, p_w1, enc_b1 + i * DFF_DIM, nullptr, 0, ffhb, 4096, 1024, 1024, 32, nullptr, HUGE_COL, 0, 0, 0);
        if (!big) cvt_wt<false><<<dim3(16, 64, 1), blk, 0, stream>>>(enc_w2 + (size_t)i * SZ_FF, p_w2, 4096, 1024, 0, 0);
        if (big) {
            gemm_bt<128, 3, false><<<dim3(128, 1, 4), blk, 0, stream>>>(ffhb, p_w2, nullptr, nullptr, 0, part, 1024, 4096, 1024, 8, nullptr, HUGE_COL, 0, 0, 0);
            ln_red<4><<<NTOK, blk, 0, stream>>>(part, enc_b2 + i * E_DIM, xe, lg1, lb1, xeb);
        } else {
            gemm_bt<64, 2, false><<<dim3(256, 1, 1), blk, 0, stream>>>(ffhb, p_w2, enc_b2 + i * E_DIM, xe, 1024, xe, 1024, 4096, 4096, 8, nullptr, HUGE_COL, 0, 0, 0);
            ln_kernel<<<NTOK, blk, 0, stream>>>(xe, lg1, lb1, xeb);
        }
    }

    // ---- batched cross K/V for all 4 decoder layers (big path) ----
    if (big) {
        gemm_bt<128, 0, true><<<dim3(256, 1, 4), blk, 0, stream>>>(
            xeb, wtbase + o_dqc + SZ_E, nullptr, nullptr, 0,
            ckb, 1024, 1024, 1024, 16, cvtb, 1024,
            SZ_QKV, 2 * SZ_E, 2 * SZ_E);
    }

    // -------- decoder --------
    for (int i = 0; i < 4; ++i) {
        u16* p_qkv = big ? wtbase + o_dqs  + i * SZ_QKV : wtbase;
        u16* p_wos = big ? wtbase + o_dwos + i * SZ_E   : wtbase;
        u16* p_qc  = big ? wtbase + o_dqc  + i * SZ_QKV : wtbase;
        u16* p_woc = big ? wtbase + o_dwoc + i * SZ_E   : wtbase;
        u16* p_w1  = big ? wtbase + o_dw1  + i * SZ_FF  : wtbase;
        u16* p_w2  = big ? wtbase + o_dw2  + i * SZ_FF  : wtbase;
        const float* lg0 = dlg + (size_t)(i * 3 + 0) * E_DIM;
        const float* lb0 = dlb + (size_t)(i * 3 + 0) * E_DIM;
        const float* lg1 = dlg + (size_t)(i * 3 + 1) * E_DIM;
        const float* lb1 = dlb + (size_t)(i * 3 + 1) * E_DIM;
        const float* lg2 = dlg + (size_t)(i * 3 + 2) * E_DIM;
        const float* lb2 = dlb + (size_t)(i * 3 + 2) * E_DIM;

        if (!big) cvt_wt<true><<<dim3(48, 16, 1), blk, 0, stream>>>(dq_s + i * WQKV_L, p_qkv, 1024, 3072, 0, 0);
        gemm_bt<128, 0, false><<<dim3(384, 1, 1), blk, 0, stream>>>(yb, p_qkv, nullptr, nullptr, 0, qkvb, 3072, 1024, 1024, 24, vt, 2048, 0, 0, 0);
        attn_mfma<true><<<g_attn, blk, 0, stream>>>(qkvb, 3072, qkvb + 1024, 3072, vt, attb, 0.125f);
        if (!big) cvt_wt<false><<<dim3(16, 16, 1), blk, 0, stream>>>(dwo_s + (size_t)i * SZ_E, p_wos, 1024, 1024, 0, 0);
        if (big) {
            gemm_bt<64, 3, false><<<dim3(256, 1, 2), blk, 0, stream>>>(attb, p_wos, nullptr, nullptr, 0, part, 1024, 1024, 512, 8, nullptr, HUGE_COL, 0, 0, 0);
            ln_red<2><<<NTOK, blk, 0, stream>>>(part, dbo_s + i * E_DIM, y, lg0, lb0, yb);
        } else {
            gemm_bt<64, 2, false><<<dim3(256, 1, 1), blk, 0, stream>>>(attb, p_wos, dbo_s + i * E_DIM, y, 1024, y, 1024, 1024, 1024, 8, nullptr, HUGE_COL, 0, 0, 0);
            ln_kernel<<<NTOK, blk, 0, stream>>>(y, lg0, lb0, yb);
        }
        // cross-attention
        if (!big) cvt_wt<true><<<dim3(48, 16, 1), blk, 0, stream>>>(dq_c + i * WQKV_L, p_qc, 1024, 3072, 0, 0);
        gemm_bt<64, 0, false><<<dim3(256, 1, 1), blk, 0, stream>>>(yb, p_qc, nullptr, nullptr, 0, qkvb, 3072, 1024, 1024, 8, nullptr, HUGE_COL, 0, 0, 0);
        if (big) {
            attn_mfma<false><<<g_attn, blk, 0, stream>>>(qkvb, 3072, ckb + (size_t)i * 2 * SZ_E, 1024,
                                                         cvtb + (size_t)i * 2 * SZ_E, attb, 0.125f);
        } else {
            gemm_bt<64, 0, false><<<dim3(512, 1, 1), blk, 0, stream>>>(xeb, p_qc + SZ_E, nullptr, nullptr, 0, qkvb + 1024, 3072, 1024, 1024, 16, vt, 1024, 0, 0, 0);
            attn_mfma<false><<<g_attn, blk, 0, stream>>>(qkvb, 3072, qkvb + 1024, 3072, vt, attb, 0.125f);
        }
        if (!big) cvt_wt<false><<<dim3(16, 16, 1), blk, 0, stream>>>(dwo_c + (size_t)i * SZ_E, p_woc, 1024, 1024, 0, 0);
        if (big) {
            gemm_bt<64, 3, false><<<dim3(256, 1, 2), blk, 0, stream>>>(attb, p_woc, nullptr, nullptr, 0, part, 1024, 1024, 512, 8, nullptr, HUGE_COL, 0, 0, 0);
            ln_red<2><<<NTOK, blk, 0, stream>>>(part, dbo_c + i * E_DIM, y, lg1, lb1, yb);
        } else {
            gemm_bt<64, 2, false><<<dim3(256, 1, 1), blk, 0, stream>>>(attb, p_woc, dbo_c + i * E_DIM, y, 1024, y, 1024, 1024, 1024, 8, nullptr, HUGE_COL, 0, 0, 0);
            ln_kernel<<<NTOK, blk, 0, stream>>>(y, lg1, lb1, yb);
        }
        // FFN
        if (!big) cvt_wt<false><<<dim3(64, 16, 1), blk, 0, stream>>>(dw1 + (size_t)i * SZ_FF, p_w1, 1024, 4096, 0, 0);
        gemm_bt<128, 1, false><<<dim3(512, 1, 1), blk, 0, stream>>>(yb, p_w1, db1 + i * DFF_DIM, nullptr, 0, ffhb, 4096, 1024, 1024, 32, nullptr, HUGE_COL, 0, 0, 0);
        if (!big) cvt_wt<false><<<dim3(16, 64, 1), blk, 0, stream>>>(dw2 + (size_t)i * SZ_FF, p_w2, 4096, 1024, 0, 0);
        if (big) {
            gemm_bt<128, 3, false><<<dim3(128, 1, 4), blk, 0, stream>>>(ffhb, p_w2, nullptr, nullptr, 0, part, 1024, 4096, 1024, 8, nullptr, HUGE_COL, 0, 0, 0);
            ln_red<4><<<NTOK, blk, 0, stream>>>(part, db2 + i * E_DIM, y, lg2, lb2, yb);
        } else {
            gemm_bt<64, 2, false><<<dim3(256, 1, 1), blk, 0, stream>>>(ffhb, p_w2, db2 + i * E_DIM, y, 1024, y, 1024, 4096, 4096, 8, nullptr, HUGE_COL, 0, 0, 0);
            ln_kernel<<<NTOK, blk, 0, stream>>>(y, lg2, lb2, yb);
        }
    }

    writeout<<<(NTOK * E_DIM) / 256, blk, 0, stream>>>(y, (float*)d_out);
}

// Round 20
// 1590.526 us; speedup vs baseline: 1.5111x; 1.0023x over previous
//
#include <hip/hip_runtime.h>
#include <hip/hip_bf16.h>

typedef __hip_bfloat16 bf16;
typedef unsigned short u16;
typedef u16 u16x4 __attribute__((ext_vector_type(4)));
typedef u16 u16x8 __attribute__((ext_vector_type(8)));
typedef __bf16 bf16x8 __attribute__((ext_vector_type(8)));
typedef float f32x4 __attribute__((ext_vector_type(4)));

#define E_DIM 1024
#define DFF_DIM 4096
#define B_SZ 4
#define S_LEN 512
#define NTOK 2048

__device__ __forceinline__ u16 f2bf(float f) {
    unsigned u = __float_as_uint(f);
    return (u16)((u + 0x7FFFu + ((u >> 16) & 1u)) >> 16);
}
__device__ __forceinline__ void gload_lds16(const u16* g, u16* l) {
    __builtin_amdgcn_global_load_lds(
        (const __attribute__((address_space(1))) unsigned int*)g,
        (__attribute__((address_space(3))) unsigned int*)l, 16, 0, 0);
}

// ---------- transpose in: (S,B,E) f32 -> (B,S,E) f32 + bf16 ----------
__global__ __launch_bounds__(256) void transpose_in(const float* __restrict__ in,
                                                    float* __restrict__ out,
                                                    u16* __restrict__ outb) {
    size_t i = (size_t)blockIdx.x * 256 + threadIdx.x;
    int e = (int)(i & 1023);
    int sb = (int)(i >> 10);
    int b = sb & 3;
    int s = sb >> 2;
    float v = in[i];
    size_t o = ((size_t)((b << 9) + s) << 10) + e;
    out[o] = v;
    outb[o] = f2bf(v);
}

// ---------- writeout: (B,S,E) f32 -> (S,B,E) f32 ----------
__global__ __launch_bounds__(256) void writeout(const float* __restrict__ y,
                                                float* __restrict__ out) {
    size_t i = (size_t)blockIdx.x * 256 + threadIdx.x;
    int e = (int)(i & 1023);
    int sb = (int)(i >> 10);
    int b = sb & 3;
    int s = sb >> 2;
    out[i] = y[((size_t)((b << 9) + s) << 10) + e];
}

// ---- weight transpose+cvt (layer-batched, float4 loads): W f32 -> Wt bf16 [N][K] ----
template<bool QKV>
__global__ __launch_bounds__(256) void cvt_wt(const float* __restrict__ W,
                                              u16* __restrict__ Wt, int K, int N,
                                              size_t wls, size_t wtls) {
    const float* Wl = W + (size_t)blockIdx.z * wls;
    u16* Wtl = Wt + (size_t)blockIdx.z * wtls;
    __shared__ u16 ts[64][72];
    const int n0 = blockIdx.x * 64, k0 = blockIdx.y * 64;
    #pragma unroll
    for (int r = 0; r < 4; ++r) {
        int idx = threadIdx.x + r * 256;     // float4 index within 64x64 tile
        int k = idx >> 4;                    // 16 float4 per k-row
        int n4 = (idx & 15) * 4;
        const float* p;
        if (QKV) p = &Wl[(size_t)(n0 >> 6) * ((size_t)K * 64) + (size_t)(k0 + k) * 64 + n4];
        else     p = &Wl[(size_t)(k0 + k) * N + n0 + n4];
        const float4 v = *reinterpret_cast<const float4*>(p);
        ts[n4 + 0][k] = f2bf(v.x);
        ts[n4 + 1][k] = f2bf(v.y);
        ts[n4 + 2][k] = f2bf(v.z);
        ts[n4 + 3][k] = f2bf(v.w);
    }
    __syncthreads();
    #pragma unroll
    for (int r = 0; r < 2; ++r) {
        int idx = threadIdx.x + r * 256;
        int n = idx >> 3, c = idx & 7;
        u16x8 vv = *reinterpret_cast<const u16x8*>(&ts[n][c * 8]);
        *reinterpret_cast<u16x8*>(Wtl + (size_t)(n0 + n) * K + k0 + c * 8) = vv;
    }
}

// == bf16 GEMM v8: depth-2 + counted vmcnt + LDS swizzle + coalesced V^T epilogue ==
// EPI: 0 = bf16 out (whole 128-col V tiles at n0>=vcol0 transposed coalesced);
//      1 = bf16 bias+relu; 2 = f32 bias+residual; 3 = f32 partial (split-K).
// BATCH: blockIdx.z = layer; else z = K-slice.
template<int BM, int EPI, bool BATCH>
__global__ __launch_bounds__(256) void gemm_bt(
    const u16* __restrict__ A,
    const u16* __restrict__ Bt,
    const float* __restrict__ bias,
    const float* __restrict__ Res, int ldres,
    void* __restrict__ Cout, int ldc, int Kfull, int KS, int gx,
    u16* __restrict__ vtout, int vcol0,
    size_t bstr, size_t cstr, size_t vstr)
{
    constexpr int MR = BM / 32;
    constexpr int AOPS = BM / 16;
    constexpr int BOPS = 8;
    constexpr int OPW = AOPS / 4 + BOPS / 4;
    __shared__ u16 SH[3 * BM * 32 + 3 * 128 * 32];
    u16* As = SH;
    u16* Bs = SH + 3 * BM * 32;
    const int tid = threadIdx.x;
    const int l = tid & 63, w = tid >> 6;
    const int nwg = gridDim.x;
    const int lin = blockIdx.x;
    const int wg = (lin & 7) * (nwg >> 3) + (lin >> 3);   // bijective XCD swizzle
    const int m0 = (wg / gx) * BM, n0 = (wg % gx) * 128;
    const int z = blockIdx.z;
    const int mw = (w >> 1) * (BM / 2), nw = (w & 1) * 64;
    const int lr = l & 15, lg = l >> 4;
    const int srow = l >> 2;
    const int schunk = (((l & 3) ^ ((l >> 3) & 3))) * 8;   // swizzled global source
    const int rsw = (lr >> 1) & 3;                          // read-side chunk XOR

    const u16* bt = Bt;
    u16* vto = vtout;
    size_t coff = 0;
    int koff = z * KS;
    if constexpr (BATCH) {
        bt += (size_t)z * bstr;
        vto += (size_t)z * vstr;
        coff = (size_t)z * cstr;
        koff = 0;
    }

    f32x4 acc[MR][4];
    #pragma unroll
    for (int mi = 0; mi < MR; ++mi)
        #pragma unroll
        for (int ni = 0; ni < 4; ++ni) acc[mi][ni] = (f32x4)(0.0f);

    const u16* ap = A + (size_t)(m0 + srow) * Kfull + koff + schunk;
    const u16* bp = bt + (size_t)(n0 + srow) * Kfull + koff + schunk;
    const int nt = KS / 32;

    // prologue: stage tiles 0 and 1
    #pragma unroll
    for (int op = w; op < AOPS; op += 4) gload_lds16(ap + (size_t)op * 16 * Kfull, &As[op * 512]);
    #pragma unroll
    for (int op = w; op < BOPS; op += 4) gload_lds16(bp + (size_t)op * 16 * Kfull, &Bs[op * 512]);
    #pragma unroll
    for (int op = w; op < AOPS; op += 4) gload_lds16(ap + (size_t)op * 16 * Kfull + 32, &As[BM * 32 + op * 512]);
    #pragma unroll
    for (int op = w; op < BOPS; op += 4) gload_lds16(bp + (size_t)op * 16 * Kfull + 32, &Bs[128 * 32 + op * 512]);

    for (int k = 0; k < nt; ++k) {
        if (k + 2 < nt) {
            const int kk = (k + 2) * 32;
            const int buf = (k + 2) % 3;
            #pragma unroll
            for (int op = w; op < AOPS; op += 4) gload_lds16(ap + (size_t)op * 16 * Kfull + kk, &As[buf * BM * 32 + op * 512]);
            #pragma unroll
            for (int op = w; op < BOPS; op += 4) gload_lds16(bp + (size_t)op * 16 * Kfull + kk, &Bs[buf * 128 * 32 + op * 512]);
            asm volatile("s_waitcnt vmcnt(%0)" :: "i"(2 * OPW) : "memory");
        } else if (k + 1 < nt) {
            asm volatile("s_waitcnt vmcnt(%0)" :: "i"(OPW) : "memory");
        } else {
            asm volatile("s_waitcnt vmcnt(0)" ::: "memory");
        }
        __builtin_amdgcn_s_barrier();

        const int buf = k % 3;
        u16x8 af[MR], bfr[4];
        #pragma unroll
        for (int mi = 0; mi < MR; ++mi)
            af[mi] = *reinterpret_cast<const u16x8*>(
                &As[buf * BM * 32 + (mw + mi * 16 + lr) * 32 + ((lg ^ rsw) * 8)]);
        #pragma unroll
        for (int ni = 0; ni < 4; ++ni)
            bfr[ni] = *reinterpret_cast<const u16x8*>(
                &Bs[buf * 128 * 32 + (nw + ni * 16 + lr) * 32 + ((lg ^ rsw) * 8)]);
        #pragma unroll
        for (int mi = 0; mi < MR; ++mi)
            #pragma unroll
            for (int ni = 0; ni < 4; ++ni)
                acc[mi][ni] = __builtin_amdgcn_mfma_f32_16x16x32_bf16(
                    __builtin_bit_cast(bf16x8, af[mi]),
                    __builtin_bit_cast(bf16x8, bfr[ni]),
                    acc[mi][ni], 0, 0, 0);
        __builtin_amdgcn_s_barrier();   // write-guard
    }

    if constexpr (EPI == 0) {
        if (n0 >= vcol0) {
            // ---- V tile: LDS transpose [n_local][m_local] then coalesced write ----
            constexpr int PSTR = BM + 4;
            #pragma unroll
            for (int mi = 0; mi < MR; ++mi)
                #pragma unroll
                for (int ni = 0; ni < 4; ++ni) {
                    const int nl = nw + ni * 16 + lr;
                    #pragma unroll
                    for (int r = 0; r < 4; ++r)
                        SH[nl * PSTR + mw + mi * 16 + lg * 4 + r] = f2bf(acc[mi][ni][r]);
                }
            __syncthreads();
            constexpr int LPR = BM / 8;          // lanes per row (16B chunks)
            constexpr int RPP = 256 / LPR;       // rows per pass
            const int row = tid / LPR, j = tid % LPR;
            const int bb = m0 >> 9, tt0 = m0 & 511;
            #pragma unroll
            for (int p = 0; p < 128 / RPP; ++p) {
                const int rr = p * RPP + row;
                const int d = n0 + rr - vcol0;
                u16x8 vv = *reinterpret_cast<const u16x8*>(&SH[rr * PSTR + j * 8]);
                *reinterpret_cast<u16x8*>(
                    vto + ((size_t)((bb * 16 + (d >> 6)) * 64 + (d & 63))) * 512 + tt0 + j * 8) = vv;
            }
            return;
        }
    }

    #pragma unroll
    for (int mi = 0; mi < MR; ++mi) {
        #pragma unroll
        for (int ni = 0; ni < 4; ++ni) {
            const int gc = n0 + nw + ni * 16 + lr;
            float bv = 0.0f;
            if constexpr (EPI == 1 || EPI == 2) bv = bias[gc];
            #pragma unroll
            for (int r = 0; r < 4; ++r) {
                const int gr = m0 + mw + mi * 16 + lg * 4 + r;
                float v = acc[mi][ni][r] + bv;
                if constexpr (EPI == 1) v = fmaxf(v, 0.0f);
                if constexpr (EPI == 2) {
                    ((float*)Cout)[(size_t)gr * ldc + gc] = v + Res[(size_t)gr * ldres + gc];
                } else if constexpr (EPI == 3) {
                    ((float*)Cout)[(size_t)z * NTOK * ldc + (size_t)gr * ldc + gc] = v;
                } else {
                    ((u16*)Cout + coff)[(size_t)gr * ldc + gc] = f2bf(v);
                }
            }
        }
    }
}

// ---------- fused split-K reduce + bias + residual + LayerNorm ----------
template<int NP>
__global__ __launch_bounds__(256) void ln_red(
    const float* __restrict__ part, const float* __restrict__ bias,
    float* __restrict__ X,
    const float* __restrict__ g, const float* __restrict__ bta,
    u16* __restrict__ outb) {
    __shared__ float wred[4];
    __shared__ float stat;
    const size_t row = blockIdx.x;
    const int tid = threadIdx.x;
    float4 v = reinterpret_cast<const float4*>(X + (row << 10))[tid];
    const float4 bb = reinterpret_cast<const float4*>(bias)[tid];
    v.x += bb.x; v.y += bb.y; v.z += bb.z; v.w += bb.w;
    #pragma unroll
    for (int s = 0; s < NP; ++s) {
        const float4 p = reinterpret_cast<const float4*>(part + ((size_t)s * NTOK + row) * 1024)[tid];
        v.x += p.x; v.y += p.y; v.z += p.z; v.w += p.w;
    }
    float sm = v.x + v.y + v.z + v.w;
    #pragma unroll
    for (int off = 32; off; off >>= 1) sm += __shfl_down(sm, off, 64);
    if ((tid & 63) == 0) wred[tid >> 6] = sm;
    __syncthreads();
    if (tid == 0) stat = (wred[0] + wred[1] + wred[2] + wred[3]) * (1.0f / 1024.0f);
    __syncthreads();
    float m = stat;
    float dx = v.x - m, dy = v.y - m, dz = v.z - m, dw = v.w - m;
    float s2 = dx * dx + dy * dy + dz * dz + dw * dw;
    #pragma unroll
    for (int off = 32; off; off >>= 1) s2 += __shfl_down(s2, off, 64);
    __syncthreads();
    if ((tid & 63) == 0) wred[tid >> 6] = s2;
    __syncthreads();
    if (tid == 0) stat = rsqrtf((wred[0] + wred[1] + wred[2] + wred[3]) * (1.0f / 1024.0f) + 1e-5f);
    __syncthreads();
    float r = stat;
    const float4 gv = reinterpret_cast<const float4*>(g)[tid];
    const float4 bv = reinterpret_cast<const float4*>(bta)[tid];
    float4 o;
    o.x = dx * r * gv.x + bv.x;
    o.y = dy * r * gv.y + bv.y;
    o.z = dz * r * gv.z + bv.z;
    o.w = dw * r * gv.w + bv.w;
    reinterpret_cast<float4*>(X + (row << 10))[tid] = o;
    u16x4 ob;
    ob.x = f2bf(o.x); ob.y = f2bf(o.y); ob.z = f2bf(o.z); ob.w = f2bf(o.w);
    *reinterpret_cast<u16x4*>(outb + (row << 10) + (tid << 2)) = ob;
}

// ---------- plain layernorm (fallback path) ----------
__global__ __launch_bounds__(256) void ln_kernel(float* __restrict__ X,
        const float* __restrict__ g, const float* __restrict__ bta,
        u16* __restrict__ outb) {
    __shared__ float wred[4];
    __shared__ float stat;
    float* x = X + ((size_t)blockIdx.x << 10);
    const int tid = threadIdx.x;
    float4 v = reinterpret_cast<float4*>(x)[tid];
    float s = v.x + v.y + v.z + v.w;
    #pragma unroll
    for (int off = 32; off; off >>= 1) s += __shfl_down(s, off, 64);
    if ((tid & 63) == 0) wred[tid >> 6] = s;
    __syncthreads();
    if (tid == 0) stat = (wred[0] + wred[1] + wred[2] + wred[3]) * (1.0f / 1024.0f);
    __syncthreads();
    float m = stat;
    float dx = v.x - m, dy = v.y - m, dz = v.z - m, dw = v.w - m;
    float s2 = dx * dx + dy * dy + dz * dz + dw * dw;
    #pragma unroll
    for (int off = 32; off; off >>= 1) s2 += __shfl_down(s2, off, 64);
    __syncthreads();
    if ((tid & 63) == 0) wred[tid >> 6] = s2;
    __syncthreads();
    if (tid == 0) stat = rsqrtf((wred[0] + wred[1] + wred[2] + wred[3]) * (1.0f / 1024.0f) + 1e-5f);
    __syncthreads();
    float r = stat;
    const float4 gv = reinterpret_cast<const float4*>(g)[tid];
    const float4 bv = reinterpret_cast<const float4*>(bta)[tid];
    float4 o;
    o.x = dx * r * gv.x + bv.x;
    o.y = dy * r * gv.y + bv.y;
    o.z = dz * r * gv.z + bv.z;
    o.w = dw * r * gv.w + bv.w;
    reinterpret_cast<float4*>(x)[tid] = o;
    u16x4 ob;
    ob.x = f2bf(o.x); ob.y = f2bf(o.y); ob.z = f2bf(o.z); ob.w = f2bf(o.w);
    *reinterpret_cast<u16x4*>(outb + ((size_t)blockIdx.x << 10) + (tid << 2)) = ob;
}

// ======= MFMA attention v5: swapped QK^T, in-reg softmax, coalesced O write =======
template<bool CAUSAL>
__global__ __launch_bounds__(256) void attn_mfma(
    const u16* __restrict__ Qb, int ldq,
    const u16* __restrict__ Kb, int ldk,
    const u16* __restrict__ Vt, u16* __restrict__ Ob, float inv_scale)
{
    __shared__ u16 sP[16][520];
    __shared__ float sMax[4][16];
    __shared__ float sSum[4][16];
    const int qt = blockIdx.x, h = blockIdx.y, b = blockIdx.z;
    const int tid = threadIdx.x;
    const int l = tid & 63, w = tid >> 6;
    const int lr = l & 15, lg = l >> 4;
    const int q = lr;
    const int tmax = CAUSAL ? (qt + 1) * 16 : 512;
    const int KT = CAUSAL ? ((qt + 2) >> 1) : 16;
    const int KT32 = KT * 32;

    const u16* qbase = Qb + (size_t)(b * 512 + qt * 16 + lr) * ldq + h * 64 + lg * 8;
    u16x8 qf0 = *reinterpret_cast<const u16x8*>(qbase);
    u16x8 qf1 = *reinterpret_cast<const u16x8*>(qbase + 32);

    f32x4 sacc[8];
    __builtin_amdgcn_s_setprio(1);
    #pragma unroll
    for (int ni = 0; ni < 8; ++ni) {
        const int t0 = w * 128 + ni * 16;
        if (CAUSAL && t0 >= tmax) { sacc[ni] = (f32x4)(-3.0e38f); continue; }
        const u16* kbase = Kb + (size_t)(b * 512 + t0 + lr) * ldk + h * 64 + lg * 8;
        u16x8 kf0 = *reinterpret_cast<const u16x8*>(kbase);
        u16x8 kf1 = *reinterpret_cast<const u16x8*>(kbase + 32);
        f32x4 sa = (f32x4)(0.0f);
        sa = __builtin_amdgcn_mfma_f32_16x16x32_bf16(
            __builtin_bit_cast(bf16x8, kf0), __builtin_bit_cast(bf16x8, qf0), sa, 0, 0, 0);
        sa = __builtin_amdgcn_mfma_f32_16x16x32_bf16(
            __builtin_bit_cast(bf16x8, kf1), __builtin_bit_cast(bf16x8, qf1), sa, 0, 0, 0);
        sacc[ni] = sa;
    }
    __builtin_amdgcn_s_setprio(0);
    float mx = -3.0e38f;
    #pragma unroll
    for (int ni = 0; ni < 8; ++ni) {
        const int t0 = w * 128 + ni * 16;
        #pragma unroll
        for (int r = 0; r < 4; ++r) {
            const int t = t0 + lg * 4 + r;
            float v = sacc[ni][r] * inv_scale;
            if (CAUSAL && t > qt * 16 + q) v = -3.0e38f;
            sacc[ni][r] = v;
            mx = fmaxf(mx, v);
        }
    }
    mx = fmaxf(mx, __shfl_xor(mx, 16));
    mx = fmaxf(mx, __shfl_xor(mx, 32));
    if (lg == 0) sMax[w][lr] = mx;
    __syncthreads();
    mx = fmaxf(fmaxf(sMax[0][q], sMax[1][q]), fmaxf(sMax[2][q], sMax[3][q]));

    float sum = 0.0f;
    #pragma unroll
    for (int ni = 0; ni < 8; ++ni)
        #pragma unroll
        for (int r = 0; r < 4; ++r) {
            float x = sacc[ni][r] - mx;
            float p = (x < -80.0f) ? 0.0f : __expf(x);
            sacc[ni][r] = p;
            sum += p;
        }
    sum += __shfl_xor(sum, 16);
    sum += __shfl_xor(sum, 32);
    if (lg == 0) sSum[w][lr] = sum;
    __syncthreads();
    const float inv = 1.0f / (sSum[0][q] + sSum[1][q] + sSum[2][q] + sSum[3][q]);

    const int sw = (q & 7) << 3;
    #pragma unroll
    for (int ni = 0; ni < 8; ++ni) {
        const int t0 = w * 128 + ni * 16;
        if (CAUSAL && t0 >= KT32) break;
        const int tb = t0 + lg * 4;
        unsigned p01 = (unsigned)f2bf(sacc[ni][0] * inv) | ((unsigned)f2bf(sacc[ni][1] * inv) << 16);
        unsigned p23 = (unsigned)f2bf(sacc[ni][2] * inv) | ((unsigned)f2bf(sacc[ni][3] * inv) << 16);
        *reinterpret_cast<unsigned*>(&sP[q][tb ^ sw]) = p01;
        *reinterpret_cast<unsigned*>(&sP[q][(tb + 2) ^ sw]) = p23;
    }
    __syncthreads();

    const u16* vbase = Vt + ((size_t)((b * 16 + h) * 64 + w * 16 + lr)) * 512 + lg * 8;
    const int swr = (lr & 7) << 3;
    f32x4 oa = (f32x4)(0.0f);
    __builtin_amdgcn_s_setprio(1);
    #pragma unroll 4
    for (int kt = 0; kt < KT; ++kt) {
        u16x8 pf = *reinterpret_cast<const u16x8*>(&sP[lr][(kt * 32 + lg * 8) ^ swr]);
        u16x8 vf = *reinterpret_cast<const u16x8*>(vbase + kt * 32);
        oa = __builtin_amdgcn_mfma_f32_16x16x32_bf16(
            __builtin_bit_cast(bf16x8, pf), __builtin_bit_cast(bf16x8, vf), oa, 0, 0, 0);
    }
    __builtin_amdgcn_s_setprio(0);

    // ---- coalesced O write: stage 16x64 tile in LDS, write 128B rows ----
    __syncthreads();                         // all sP reads done
    u16* sO = &sP[0][0];                     // reuse (2 KB needed)
    #pragma unroll
    for (int r = 0; r < 4; ++r)
        sO[(lg * 4 + r) * 64 + w * 16 + lr] = f2bf(oa[r]);
    __syncthreads();
    {
        const int row = tid >> 4, c4 = (tid & 15) * 4;
        u16x4 vv = *reinterpret_cast<const u16x4*>(&sO[row * 64 + c4]);
        *reinterpret_cast<u16x4*>(
            Ob + (size_t)(b * 512 + qt * 16 + row) * 1024 + h * 64 + c4) = vv;
    }
}

extern "C" void kernel_launch(void* const* d_in, const int* in_sizes, int n_in,
                              void* d_out, int out_size, void* d_ws, size_t ws_size,
                              hipStream_t stream) {
    const float* src      = (const float*)d_in[0];
    const float* tgt      = (const float*)d_in[1];
    const float* enc_wqkv = (const float*)d_in[6];
    const float* enc_wo   = (const float*)d_in[7];
    const float* enc_bo   = (const float*)d_in[8];
    const float* enc_w1   = (const float*)d_in[9];
    const float* enc_b1   = (const float*)d_in[10];
    const float* enc_w2   = (const float*)d_in[11];
    const float* enc_b2   = (const float*)d_in[12];
    const float* enc_lg   = (const float*)d_in[13];
    const float* enc_lb   = (const float*)d_in[14];
    const float* dq_s     = (const float*)d_in[15];
    const float* dwo_s    = (const float*)d_in[16];
    const float* dbo_s    = (const float*)d_in[17];
    const float* dq_c     = (const float*)d_in[18];
    const float* dwo_c    = (const float*)d_in[19];
    const float* dbo_c    = (const float*)d_in[20];
    const float* dw1      = (const float*)d_in[21];
    const float* db1      = (const float*)d_in[22];
    const float* dw2      = (const float*)d_in[23];
    const float* db2      = (const float*)d_in[24];
    const float* dlg      = (const float*)d_in[25];
    const float* dlb      = (const float*)d_in[26];

    // ---- activations (40 MB) ----
    float* xe = (float*)d_ws;
    float* y  = xe + (size_t)NTOK * E_DIM;
    u16* xeb  = (u16*)(y + (size_t)NTOK * E_DIM);
    u16* yb   = xeb  + (size_t)NTOK * E_DIM;
    u16* qkvb = yb   + (size_t)NTOK * E_DIM;
    u16* attb = qkvb + (size_t)NTOK * 3 * E_DIM;
    u16* ffhb = qkvb;                           // alias
    u16* wtbase = attb + (size_t)NTOK * E_DIM;

    const size_t SZ_QKV = (size_t)3072 * 1024;
    const size_t SZ_E   = (size_t)1024 * 1024;
    const size_t SZ_FF  = (size_t)4096 * 1024;
    const size_t o_eqkv = 0;
    const size_t o_ewo  = o_eqkv + 4 * SZ_QKV;
    const size_t o_ew1  = o_ewo  + 4 * SZ_E;
    const size_t o_ew2  = o_ew1  + 4 * SZ_FF;
    const size_t o_dqs  = o_ew2  + 4 * SZ_FF;
    const size_t o_dwos = o_dqs  + 4 * SZ_QKV;
    const size_t o_dqc  = o_dwos + 4 * SZ_E;
    const size_t o_dwoc = o_dqc  + 4 * SZ_QKV;
    const size_t o_dw1  = o_dwoc + 4 * SZ_E;
    const size_t o_dw2  = o_dw1  + 4 * SZ_FF;
    const size_t o_vt   = o_dw2  + 4 * SZ_FF;
    const size_t o_part = o_vt   + 2 * SZ_E;
    const size_t o_ck   = o_part + 16 * SZ_E;
    const size_t o_cvt  = o_ck   + 8 * SZ_E;
    const size_t act_bytes = (size_t)40 * 1024 * 1024;
    const size_t need_big = act_bytes + (o_cvt + 8 * SZ_E) * 2;
    const bool big = ws_size >= need_big;

    u16* vt   = big ? (wtbase + o_vt) : (wtbase + SZ_FF);
    float* part = big ? (float*)(wtbase + o_part) : nullptr;
    u16* ckb  = big ? (wtbase + o_ck) : nullptr;
    u16* cvtb = big ? (wtbase + o_cvt) : nullptr;
    const int HUGE_COL = 1 << 30;

    const size_t WQKV_L = 3 * (size_t)16 * E_DIM * 64;
    const dim3 blk(256);
    const dim3 g_attn(S_LEN / 16, 16, B_SZ);

    transpose_in<<<(NTOK * E_DIM) / 256, blk, 0, stream>>>(src, xe, xeb);
    transpose_in<<<(NTOK * E_DIM) / 256, blk, 0, stream>>>(tgt, y, yb);

    if (big) {
        cvt_wt<true ><<<dim3(48, 16, 4), blk, 0, stream>>>(enc_wqkv, wtbase + o_eqkv, 1024, 3072, WQKV_L, SZ_QKV);
        cvt_wt<false><<<dim3(16, 16, 4), blk, 0, stream>>>(enc_wo,   wtbase + o_ewo,  1024, 1024, SZ_E, SZ_E);
        cvt_wt<false><<<dim3(64, 16, 4), blk, 0, stream>>>(enc_w1,   wtbase + o_ew1,  1024, 4096, SZ_FF, SZ_FF);
        cvt_wt<false><<<dim3(16, 64, 4), blk, 0, stream>>>(enc_w2,   wtbase + o_ew2,  4096, 1024, SZ_FF, SZ_FF);
        cvt_wt<true ><<<dim3(48, 16, 4), blk, 0, stream>>>(dq_s,     wtbase + o_dqs,  1024, 3072, WQKV_L, SZ_QKV);
        cvt_wt<false><<<dim3(16, 16, 4), blk, 0, stream>>>(dwo_s,    wtbase + o_dwos, 1024, 1024, SZ_E, SZ_E);
        cvt_wt<true ><<<dim3(48, 16, 4), blk, 0, stream>>>(dq_c,     wtbase + o_dqc,  1024, 3072, WQKV_L, SZ_QKV);
        cvt_wt<false><<<dim3(16, 16, 4), blk, 0, stream>>>(dwo_c,    wtbase + o_dwoc, 1024, 1024, SZ_E, SZ_E);
        cvt_wt<false><<<dim3(64, 16, 4), blk, 0, stream>>>(dw1,      wtbase + o_dw1,  1024, 4096, SZ_FF, SZ_FF);
        cvt_wt<false><<<dim3(16, 64, 4), blk, 0, stream>>>(dw2,      wtbase + o_dw2,  4096, 1024, SZ_FF, SZ_FF);
    }

    // -------- encoder --------
    for (int i = 0; i < 4; ++i) {
        u16* p_qkv = big ? wtbase + o_eqkv + i * SZ_QKV : wtbase;
        u16* p_wo  = big ? wtbase + o_ewo  + i * SZ_E   : wtbase;
        u16* p_w1  = big ? wtbase + o_ew1  + i * SZ_FF  : wtbase;
        u16* p_w2  = big ? wtbase + o_ew2  + i * SZ_FF  : wtbase;
        const float* lg0 = enc_lg + (size_t)(i * 2 + 0) * E_DIM;
        const float* lb0 = enc_lb + (size_t)(i * 2 + 0) * E_DIM;
        const float* lg1 = enc_lg + (size_t)(i * 2 + 1) * E_DIM;
        const float* lb1 = enc_lb + (size_t)(i * 2 + 1) * E_DIM;

        if (!big) cvt_wt<true><<<dim3(48, 16, 1), blk, 0, stream>>>(enc_wqkv + i * WQKV_L, p_qkv, 1024, 3072, 0, 0);
        gemm_bt<128, 0, false><<<dim3(384, 1, 1), blk, 0, stream>>>(xeb, p_qkv, nullptr, nullptr, 0, qkvb, 3072, 1024, 1024, 24, vt, 2048, 0, 0, 0);
        attn_mfma<false><<<g_attn, blk, 0, stream>>>(qkvb, 3072, qkvb + 1024, 3072, vt, attb, 0.125f);
        if (!big) cvt_wt<false><<<dim3(16, 16, 1), blk, 0, stream>>>(enc_wo + (size_t)i * SZ_E, p_wo, 1024, 1024, 0, 0);
        if (big) {
            gemm_bt<64, 3, false><<<dim3(256, 1, 2), blk, 0, stream>>>(attb, p_wo, nullptr, nullptr, 0, part, 1024, 1024, 512, 8, nullptr, HUGE_COL, 0, 0, 0);
            ln_red<2><<<NTOK, blk, 0, stream>>>(part, enc_bo + i * E_DIM, xe, lg0, lb0, xeb);
        } else {
            gemm_bt<64, 2, false><<<dim3(256, 1, 1), blk, 0, stream>>>(attb, p_wo, enc_bo + i * E_DIM, xe, 1024, xe, 1024, 1024, 1024, 8, nullptr, HUGE_COL, 0, 0, 0);
            ln_kernel<<<NTOK, blk, 0, stream>>>(xe, lg0, lb0, xeb);
        }
        if (!big) cvt_wt<false><<<dim3(64, 16, 1), blk, 0, stream>>>(enc_w1 + (size_t)i * SZ_FF, p_w1, 1024, 4096, 0, 0);
        gemm_bt<128, 1, false><<<dim3(512, 1, 1), blk, 0, stream>>>(xeb, p_w1, enc_b1 + i * DFF_DIM, nullptr, 0, ffhb, 4096, 1024, 1024, 32, nullptr, HUGE_COL, 0, 0, 0);
        if (!big) cvt_wt<false><<<dim3(16, 64, 1), blk, 0, stream>>>(enc_w2 + (size_t)i * SZ_FF, p_w2, 4096, 1024, 0, 0);
        if (big) {
            gemm_bt<128, 3, false><<<dim3(128, 1, 4), blk, 0, stream>>>(ffhb, p_w2, nullptr, nullptr, 0, part, 1024, 4096, 1024, 8, nullptr, HUGE_COL, 0, 0, 0);
            ln_red<4><<<NTOK, blk, 0, stream>>>(part, enc_b2 + i * E_DIM, xe, lg1, lb1, xeb);
        } else {
            gemm_bt<64, 2, false><<<dim3(256, 1, 1), blk, 0, stream>>>(ffhb, p_w2, enc_b2 + i * E_DIM, xe, 1024, xe, 1024, 4096, 4096, 8, nullptr, HUGE_COL, 0, 0, 0);
            ln_kernel<<<NTOK, blk, 0, stream>>>(xe, lg1, lb1, xeb);
        }
    }

    // ---- batched cross K/V for all 4 decoder layers (big path) ----
    if (big) {
        gemm_bt<128, 0, true><<<dim3(256, 1, 4), blk, 0, stream>>>(
            xeb, wtbase + o_dqc + SZ_E, nullptr, nullptr, 0,
            ckb, 1024, 1024, 1024, 16, cvtb, 1024,
            SZ_QKV, 2 * SZ_E, 2 * SZ_E);
    }

    // -------- decoder --------
    for (int i = 0; i < 4; ++i) {
        u16* p_qkv = big ? wtbase + o_dqs  + i * SZ_QKV : wtbase;
        u16* p_wos = big ? wtbase + o_dwos + i * SZ_E   : wtbase;
        u16* p_qc  = big ? wtbase + o_dqc  + i * SZ_QKV : wtbase;
        u16* p_woc = big ? wtbase + o_dwoc + i * SZ_E   : wtbase;
        u16* p_w1  = big ? wtbase + o_dw1  + i * SZ_FF  : wtbase;
        u16* p_w2  = big ? wtbase + o_dw2  + i * SZ_FF  : wtbase;
        const float* lg0 = dlg + (size_t)(i * 3 + 0) * E_DIM;
        const float* lb0 = dlb + (size_t)(i * 3 + 0) * E_DIM;
        const float* lg1 = dlg + (size_t)(i * 3 + 1) * E_DIM;
        const float* lb1 = dlb + (size_t)(i * 3 + 1) * E_DIM;
        const float* lg2 = dlg + (size_t)(i * 3 + 2) * E_DIM;
        const float* lb2 = dlb + (size_t)(i * 3 + 2) * E_DIM;

        if (!big) cvt_wt<true><<<dim3(48, 16, 1), blk, 0, stream>>>(dq_s + i * WQKV_L, p_qkv, 1024, 3072, 0, 0);
        gemm_bt<128, 0, false><<<dim3(384, 1, 1), blk, 0, stream>>>(yb, p_qkv, nullptr, nullptr, 0, qkvb, 3072, 1024, 1024, 24, vt, 2048, 0, 0, 0);
        attn_mfma<true><<<g_attn, blk, 0, stream>>>(qkvb, 3072, qkvb + 1024, 3072, vt, attb, 0.125f);
        if (!big) cvt_wt<false><<<dim3(16, 16, 1), blk, 0, stream>>>(dwo_s + (size_t)i * SZ_E, p_wos, 1024, 1024, 0, 0);
        if (big) {
            gemm_bt<64, 3, false><<<dim3(256, 1, 2), blk, 0, stream>>>(attb, p_wos, nullptr, nullptr, 0, part, 1024, 1024, 512, 8, nullptr, HUGE_COL, 0, 0, 0);
            ln_red<2><<<NTOK, blk, 0, stream>>>(part, dbo_s + i * E_DIM, y, lg0, lb0, yb);
        } else {
            gemm_bt<64, 2, false><<<dim3(256, 1, 1), blk, 0, stream>>>(attb, p_wos, dbo_s + i * E_DIM, y, 1024, y, 1024, 1024, 1024, 8, nullptr, HUGE_COL, 0, 0, 0);
            ln_kernel<<<NTOK, blk, 0, stream>>>(y, lg0, lb0, yb);
        }
        // cross-attention
        if (!big) cvt_wt<true><<<dim3(48, 16, 1), blk, 0, stream>>>(dq_c + i * WQKV_L, p_qc, 1024, 3072, 0, 0);
        gemm_bt<64, 0, false><<<dim3(256, 1, 1), blk, 0, stream>>>(yb, p_qc, nullptr, nullptr, 0, qkvb, 3072, 1024, 1024, 8, nullptr, HUGE_COL, 0, 0, 0);
        if (big) {
            attn_mfma<false><<<g_attn, blk, 0, stream>>>(qkvb, 3072, ckb + (size_t)i * 2 * SZ_E, 1024,
                                                         cvtb + (size_t)i * 2 * SZ_E, attb, 0.125f);
        } else {
            gemm_bt<64, 0, false><<<dim3(512, 1, 1), blk, 0, stream>>>(xeb, p_qc + SZ_E, nullptr, nullptr, 0, qkvb + 1024, 3072, 1024, 1024, 16, vt, 1024, 0, 0, 0);
            attn_mfma<false><<<g_attn, blk, 0, stream>>>(qkvb, 3072, qkvb + 1024, 3072, vt, attb, 0.125f);
        }
        if (!big) cvt_wt<false><<<dim3(16, 16, 1), blk, 0, stream>>>(dwo_c + (size_t)i * SZ_E, p_woc, 1024, 1024, 0, 0);
        if (big) {
            gemm_bt<64, 3, false><<<dim3(256, 1, 2), blk, 0, stream>>>(attb, p_woc, nullptr, nullptr, 0, part, 1024, 1024, 512, 8, nullptr, HUGE_COL, 0, 0, 0);
            ln_red<2><<<NTOK, blk, 0, stream>>>(part, dbo_c + i * E_DIM, y, lg1, lb1, yb);
        } else {
            gemm_bt<64, 2, false><<<dim3(256, 1, 1), blk, 0, stream>>>(attb, p_woc, dbo_c + i * E_DIM, y, 1024, y, 1024, 1024, 1024, 8, nullptr, HUGE_COL, 0, 0, 0);
            ln_kernel<<<NTOK, blk, 0, stream>>>(y, lg1, lb1, yb);
        }
        // FFN
        if (!big) cvt_wt<false><<<dim3(64, 16, 1), blk, 0, stream>>>(dw1 + (size_t)i * SZ_FF, p_w1, 1024, 4096, 0, 0);
        gemm_bt<128, 1, false><<<dim3(512, 1, 1), blk, 0, stream>>>(yb, p_w1, db1 + i * DFF_DIM, nullptr, 0, ffhb, 4096, 1024, 1024, 32, nullptr, HUGE_COL, 0, 0, 0);
        if (!big) cvt_wt<false><<<dim3(16, 64, 1), blk, 0, stream>>>(dw2 + (size_t)i * SZ_FF, p_w2, 4096, 1024, 0, 0);
        if (big) {
            gemm_bt<128, 3, false><<<dim3(128, 1, 4), blk, 0, stream>>>(ffhb, p_w2, nullptr, nullptr, 0, part, 1024, 4096, 1024, 8, nullptr, HUGE_COL, 0, 0, 0);
            ln_red<4><<<NTOK, blk, 0, stream>>>(part, db2 + i * E_DIM, y, lg2, lb2, yb);
        } else {
            gemm_bt<64, 2, false><<<dim3(256, 1, 1), blk, 0, stream>>>(ffhb, p_w2, db2 + i * E_DIM, y, 1024, y, 1024, 4096, 4096, 8, nullptr, HUGE_COL, 0, 0, 0);
            ln_kernel<<<NTOK, blk, 0, stream>>>(y, lg2, lb2, yb);
        }
    }

    writeout<<<(NTOK * E_DIM) / 256, blk, 0, stream>>>(y, (float*)d_out);
}